// Round 19
// baseline (1533.534 us; speedup 1.0000x reference)
//
#include <hip/hip_runtime.h>
#include <hip/hip_bf16.h>

// MPNN GNN: V=12500 (feat 32), E=200000 (feat 16), H=32, 6 steps.
// msg[e,o] = sum_k a[e,k]*T[src[e],k,o] + Tb[src[e],o],  a loop-invariant.
// R19: k_step at 256 threads (was 512), same NB=8/CAP=256/32KB geometry.
// Hypothesis: 512-thr workgroups don't pack 4/CU (Occ stuck ~35% across
// R12-R18 despite LDS/VGPR headroom); smaller workgroups pack finer.
// T-phase: each thread covers slots t and t+256 (jg in {t>>7, t>>7+2}) —
// bijective, w2 loads disjoint + quad-coalesced (R14 low-bit lane layout).
// Edge phase: 4 waves x TPW=4 tiles. R18's b128 h-reads kept.
// Proven stack: split-bf16 3-GEMM MFMA (absmax 0.0156), kc-streamed 32KB T,
// hidden LDS-write conflict (R15), dense edgebuild + pose scatter, one
// atomic per real (e,o), agg-rezero in k_agru.

#define NB 8   // src nodes per k_step block
#define TPW 4  // 16-edge tiles per wave per chunk (4 waves)
#define CAP 256  // padded slots per chunk

typedef __attribute__((ext_vector_type(8))) short bf16x8;
typedef __attribute__((ext_vector_type(4))) float f32x4;
typedef unsigned short ushort_t;

// ---------------- node projection: h = relu(nf@w1+b1)@w2+b2 ----------------
__global__ __launch_bounds__(256) void k_proj(
    const float* __restrict__ nf, const float* __restrict__ w1,
    const float* __restrict__ b1, const float* __restrict__ w2,
    const float* __restrict__ b2, float* __restrict__ hseq, int nV) {
  __shared__ float sw1[1024], sw2[1024], sb1[32], sb2[32];
  __shared__ float sx[8][32], st1[8][32];
  int t = threadIdx.x;
  int v0 = blockIdx.x * 8;
  for (int i = t; i < 1024; i += 256) { sw1[i] = w1[i]; sw2[i] = w2[i]; }
  if (t < 32) { sb1[t] = b1[t]; sb2[t] = b2[t]; }
  {
    int g = v0 * 32 + t;
    sx[t >> 5][t & 31] = (g < nV * 32) ? nf[g] : 0.f;
  }
  __syncthreads();
  int n = t >> 5, j = t & 31;
  float s = sb1[j];
#pragma unroll
  for (int i = 0; i < 32; i++) s += sx[n][i] * sw1[i * 32 + j];
  st1[n][j] = fmaxf(s, 0.f);
  __syncthreads();
  float h = sb2[j];
#pragma unroll
  for (int i = 0; i < 32; i++) h += st1[n][i] * sw2[i * 32 + j];
  if (v0 + n < nV) hseq[(size_t)(v0 + n) * 32 + j] = h;
}

// ---------------- CSR by src, padded to multiples of 16 --------------------
__global__ __launch_bounds__(256) void k_count(const int* __restrict__ key,
                                               int* __restrict__ counts, int nE) {
  int e = blockIdx.x * 256 + threadIdx.x;
  if (e < nE) atomicAdd(&counts[key[e]], 1);
}

__global__ __launch_bounds__(1024) void k_scan(const int* __restrict__ counts,
                                               int* __restrict__ row_ptr, int nV) {
  __shared__ int buf[1024];
  __shared__ int s_off;
  int t = threadIdx.x;
  if (t == 0) s_off = 0;
  __syncthreads();
  for (int base = 0; base < nV; base += 1024) {
    int x = (base + t < nV) ? ((counts[base + t] + 15) & ~15) : 0;  // pad to 16
    buf[t] = x;
    __syncthreads();
    for (int d = 1; d < 1024; d <<= 1) {
      int v2 = (t >= d) ? buf[t - d] : 0;
      __syncthreads();
      buf[t] += v2;
      __syncthreads();
    }
    int incl = buf[t];
    int off = s_off;
    __syncthreads();
    if (base + t < nV) row_ptr[base + t] = off + incl - x;  // exclusive
    if (t == 1023) s_off = off + incl;
    __syncthreads();
  }
  if (t == 0) row_ptr[nV] = s_off;
}

__global__ __launch_bounds__(256) void k_copy(const int* __restrict__ row_ptr,
                                              int* __restrict__ cursor, int nV) {
  int v = blockIdx.x * 256 + threadIdx.x;
  if (v < nV) cursor[v] = row_ptr[v];
}

// scatter: pose[e]=padded slot of edge e; dstp[slot]=dst (pads stay -1)
__global__ __launch_bounds__(256) void k_scatter(const int* __restrict__ key,
                                                 const int* __restrict__ dst,
                                                 int* __restrict__ cursor,
                                                 int* __restrict__ pose,
                                                 int* __restrict__ dstp, int nE) {
  int e = blockIdx.x * 256 + threadIdx.x;
  if (e < nE) {
    int p = atomicAdd(&cursor[key[e]], 1);
    pose[e] = p;
    dstp[p] = dst[e];
  }
}

// ------- edge MLP, dense over real edges -> split bf16 planes --------------
__global__ __launch_bounds__(256) void k_edgebuild(
    const float* __restrict__ ef, const float* __restrict__ w1,
    const float* __restrict__ b1, const int* __restrict__ pose,
    ushort_t* __restrict__ aq_hi, ushort_t* __restrict__ aq_lo, int nE) {
  __shared__ float sw1[16 * 128], sb1[128];
  __shared__ float sef[64][17];
  __shared__ int spos[64];
  int t = threadIdx.x;
  int e0 = blockIdx.x * 64;
  if (e0 >= nE) return;
  for (int i = t; i < 2048; i += 256) sw1[i] = w1[i];
  if (t < 128) sb1[t] = b1[t];
  for (int i = t; i < 1024; i += 256) {
    int g = e0 * 16 + i;
    sef[i >> 4][i & 15] = (g < nE * 16) ? ef[g] : 0.f;
  }
  if (t < 64) spos[t] = (e0 + t < nE) ? pose[e0 + t] : 0;
  __syncthreads();
  int c = t & 127;
#pragma unroll 1
  for (int it = 0; it < 32; ++it) {
    int el = it * 2 + (t >> 7);
    if (e0 + el < nE) {
      float s = sb1[c];
#pragma unroll
      for (int i = 0; i < 16; i++) s += sef[el][i] * sw1[i * 128 + c];
      s = fmaxf(s, 0.f);
      unsigned u = __float_as_uint(s);
      unsigned hb = u >> 16;
      float fh = __uint_as_float(hb << 16);
      unsigned lb = __float_as_uint(s - fh) >> 16;
      size_t p = (size_t)spos[el] * 128 + c;
      aq_hi[p] = (ushort_t)hb;
      aq_lo[p] = (ushort_t)lb;
    }
  }
}

// ---------------- per-step: kc-streamed T (j-split) + MFMA edges -----------
// LDS sTq (32 KB): quarter frags, ushort[(n*4 + h*2 + sp)*512 + l*8 + j]
//   = T[n][kc*32 + (l>>4)*8 + j][(l&15)+16h], sp: 0=hi 1=lo.
// 256 threads: T-phase thread covers slots t and t+256 (jg = t>>7 and
// t>>7+2); th=(t>>6)&1, tl=t&63 (R14 low-bit layout preserved).
__global__ __launch_bounds__(256) void k_step(
    const float* __restrict__ hseq, const float* __restrict__ w2,
    const float* __restrict__ b2, const ushort_t* __restrict__ aq_hi,
    const ushort_t* __restrict__ aq_lo, const int* __restrict__ rp16,
    const int* __restrict__ dstp, float* __restrict__ agg, int nV) {
  __shared__ unsigned short sTq[16384];  // 32 KB
  __shared__ float sh[NB][32];     // [n][i] — Tb phase
  __shared__ float sh_t[32][NB];   // [i][n] — T phase (b128-readable)
  __shared__ float sTb[NB][32];
  __shared__ int s_rp[NB + 1];
  int t = threadIdx.x;
  int v0 = blockIdx.x * NB;
  if (t <= NB) {
    int v = v0 + t;
    if (v > nV) v = nV;
    s_rp[t] = rp16[v];
  }
  {
    int n = t >> 5, i = t & 31, v = v0 + n;
    float hv = (v < nV) ? hseq[(size_t)v * 32 + i] : 0.f;
    sh[n][i] = hv;
    sh_t[i][n] = hv;
  }
  __syncthreads();
  int beg = s_rp[0], end = s_rp[NB];
  if (beg == end) return;  // block-uniform

  {  // Tb[n][o] = sum_i h[n][i]*e_b2[i*32+o]
    int n = t >> 5, o = t & 31;
    float s = 0.f;
#pragma unroll
    for (int i = 0; i < 32; i++) s += sh[n][i] * b2[i * 32 + o];
    sTb[n][o] = s;
  }

  // thread constants — edge phase (4 waves x TPW tiles)
  int wid = t >> 6, l = t & 63;
  int r = l & 15, kg = (l >> 4) << 3;
  // thread constants — T phase (two slots: jg0 and jg0+2)
  int jg0 = t >> 7;                 // 0..1
  int th = (t >> 6) & 1;            // h half
  int tl = t & 63;                  // fragment lane
  int tc = (tl & 15) + th * 16;     // output column c
  int tkr = (tl >> 4) << 3;         // k row-group offset

  int nrun = 0;  // monotonic node cursor for this wave's tiles
  for (int cbase = beg; cbase < end; cbase += CAP) {
    int tn[TPW];
#pragma unroll
    for (int ti = 0; ti < TPW; ti++) {
      int idx16 = cbase + (wid * TPW + ti) * 16;
      if (idx16 < end) {
        while (idx16 >= s_rp[nrun + 1]) nrun++;
        tn[ti] = nrun;
      } else
        tn[ti] = NB - 1;
    }
    f32x4 acc[TPW][2];
#pragma unroll
    for (int ti = 0; ti < TPW; ti++)
#pragma unroll
      for (int hh = 0; hh < 2; hh++) acc[ti][hh] = (f32x4){0.f, 0.f, 0.f, 0.f};

#pragma unroll 1
    for (int kc = 0; kc < 4; kc++) {
      __syncthreads();  // protect sTq from previous phase's readers
      // ---- T-quarter, j-split: 2 slots per thread, disjoint w2 loads ----
#pragma unroll
      for (int sl = 0; sl < 2; sl++) {
        int jg = jg0 + 2 * sl;
        int kbase = kc * 32 + tkr + 2 * jg;
        const float* wb = w2 + (size_t)kbase * 1024 + tc;  // + jj*1024 + i*32
        float a0[NB], a1[NB];
#pragma unroll
        for (int n = 0; n < NB; n++) { a0[n] = 0.f; a1[n] = 0.f; }
#pragma unroll 4
        for (int i = 0; i < 32; i++) {
          float w0 = wb[i * 32];
          float w1 = wb[1024 + i * 32];
          float4 sA = *(const float4*)&sh_t[i][0];
          float4 sB = *(const float4*)&sh_t[i][4];
          a0[0] += sA.x * w0; a1[0] += sA.x * w1;
          a0[1] += sA.y * w0; a1[1] += sA.y * w1;
          a0[2] += sA.z * w0; a1[2] += sA.z * w1;
          a0[3] += sA.w * w0; a1[3] += sA.w * w1;
          a0[4] += sB.x * w0; a1[4] += sB.x * w1;
          a0[5] += sB.y * w0; a1[5] += sB.y * w1;
          a0[6] += sB.z * w0; a1[6] += sB.z * w1;
          a0[7] += sB.w * w0; a1[7] += sB.w * w1;
        }
#pragma unroll
        for (int n = 0; n < NB; n++) {
          float x0 = a0[n], x1 = a1[n];
          unsigned h0 = __float_as_uint(x0) >> 16, h1 = __float_as_uint(x1) >> 16;
          unsigned l0 = __float_as_uint(x0 - __uint_as_float(h0 << 16)) >> 16;
          unsigned l1 = __float_as_uint(x1 - __uint_as_float(h1 << 16)) >> 16;
          int ub = ((n * 4 + th * 2) * 64 + tl) * 8 + 2 * jg;
          *(unsigned*)&sTq[ub] = h0 | (h1 << 16);        // sp=0 (hi)
          *(unsigned*)&sTq[ub + 512] = l0 | (l1 << 16);  // sp=1 (lo)
        }
      }
      __syncthreads();
      // ---- edge MFMA for this kc on TPW tiles ----
#pragma unroll
      for (int ti = 0; ti < TPW; ti++) {
        int idx16 = cbase + (wid * TPW + ti) * 16;
        if (idx16 < end) {
          const ushort_t* ah = aq_hi + (size_t)(idx16 + r) * 128 + kc * 32 + kg;
          const ushort_t* al = aq_lo + (size_t)(idx16 + r) * 128 + kc * 32 + kg;
          bf16x8 Ah = *(const bf16x8*)ah;
          bf16x8 Al = *(const bf16x8*)al;
          int b = tn[ti] * 2048 + l * 8;
          bf16x8 B0h = *(const bf16x8*)&sTq[b];
          bf16x8 B0l = *(const bf16x8*)&sTq[b + 512];
          bf16x8 B1h = *(const bf16x8*)&sTq[b + 1024];
          bf16x8 B1l = *(const bf16x8*)&sTq[b + 1536];
          acc[ti][0] = __builtin_amdgcn_mfma_f32_16x16x32_bf16(Ah, B0h, acc[ti][0], 0, 0, 0);
          acc[ti][0] = __builtin_amdgcn_mfma_f32_16x16x32_bf16(Al, B0h, acc[ti][0], 0, 0, 0);
          acc[ti][0] = __builtin_amdgcn_mfma_f32_16x16x32_bf16(Ah, B0l, acc[ti][0], 0, 0, 0);
          acc[ti][1] = __builtin_amdgcn_mfma_f32_16x16x32_bf16(Ah, B1h, acc[ti][1], 0, 0, 0);
          acc[ti][1] = __builtin_amdgcn_mfma_f32_16x16x32_bf16(Al, B1h, acc[ti][1], 0, 0, 0);
          acc[ti][1] = __builtin_amdgcn_mfma_f32_16x16x32_bf16(Ah, B1l, acc[ti][1], 0, 0, 0);
        }
      }
    }
    // ---- flush: one atomic per real (e,o) ----
    int er = (l >> 4) << 2;
    int c = l & 15;
#pragma unroll
    for (int ti = 0; ti < TPW; ti++) {
      int idx16 = cbase + (wid * TPW + ti) * 16;
      if (idx16 < end) {
#pragma unroll
        for (int j = 0; j < 4; j++) {
          int idx = idx16 + er + j;
          int d = dstp[idx];
          if (d >= 0) {
            atomicAdd(&agg[(size_t)d * 32 + c], acc[ti][0][j] + sTb[tn[ti]][c]);
            atomicAdd(&agg[(size_t)d * 32 + c + 16], acc[ti][1][j] + sTb[tn[ti]][c + 16]);
          }
        }
      }
    }
  }
}

// ------- fused agg-read + GRU + agg-rezero: block = 8 nodes x 32 o ---------
__global__ __launch_bounds__(256) void k_agru(
    float* __restrict__ agg, const float* __restrict__ cbias,
    const float* __restrict__ wih, const float* __restrict__ whh,
    const float* __restrict__ bih, const float* __restrict__ bhh,
    float* __restrict__ hseq, int nV) {
  __shared__ float swT[2][32 * 97];
  __shared__ float sb[2][96], scb[32];
  __shared__ float sx[8][32], shd[8][32];
  int t = threadIdx.x;
  int v0 = blockIdx.x * 8;
  for (int idx = t; idx < 3072; idx += 256) {
    int row = idx >> 5, i = idx & 31;
    swT[0][i * 97 + row] = wih[idx];
    swT[1][i * 97 + row] = whh[idx];
  }
  if (t < 96) { sb[0][t] = bih[t]; sb[1][t] = bhh[t]; }
  if (t < 32) scb[t] = cbias[t];
  {
    int n = t >> 5, v = v0 + n, j = t & 31;
    shd[n][j] = (v < nV) ? hseq[(size_t)v * 32 + j] : 0.f;
    float av = 0.f;
    if (v < nV) {
      av = agg[(size_t)v * 32 + j];
      agg[(size_t)v * 32 + j] = 0.f;  // re-zero for next step's atomics
    }
    sx[n][j] = (v < nV) ? fmaxf(av + cbias[j], 0.f) : 0.f;
  }
  __syncthreads();
  int n = t >> 5, o = t & 31;
  int v = v0 + n;
  if (v >= nV) return;
  float gir = sb[0][o], giz = sb[0][32 + o], gin = sb[0][64 + o];
  float ghr = sb[1][o], ghz = sb[1][32 + o], ghn = sb[1][64 + o];
#pragma unroll
  for (int i = 0; i < 32; i++) {
    float xi = sx[n][i], hi = shd[n][i];
    gir += xi * swT[0][i * 97 + o];
    giz += xi * swT[0][i * 97 + 32 + o];
    gin += xi * swT[0][i * 97 + 64 + o];
    ghr += hi * swT[1][i * 97 + o];
    ghz += hi * swT[1][i * 97 + 32 + o];
    ghn += hi * swT[1][i * 97 + 64 + o];
  }
  float r = 1.f / (1.f + __expf(-(gir + ghr)));
  float z = 1.f / (1.f + __expf(-(giz + ghz)));
  float ng = tanhf(gin + r * ghn);
  hseq[(size_t)v * 32 + o] = (1.f - z) * ng + z * shd[n][o];
}

// ---------------- decoder: out = relu(h@dw1+db1)@dw2+db2  (V x 64) ---------
__global__ __launch_bounds__(256) void k_dec(
    const float* __restrict__ hseq, const float* __restrict__ w1,
    const float* __restrict__ b1, const float* __restrict__ w2,
    const float* __restrict__ b2, float* __restrict__ out, int nV) {
  __shared__ float sw1[1024], sb1[32], sw2[2048], sb2[64];
  __shared__ float sx[4][32], st1[4][32];
  int t = threadIdx.x;
  int v0 = blockIdx.x * 4;
  for (int i = t; i < 1024; i += 256) sw1[i] = w1[i];
  for (int i = t; i < 2048; i += 256) sw2[i] = w2[i];
  if (t < 32) sb1[t] = b1[t];
  if (t < 64) sb2[t] = b2[t];
  if (t < 128) {
    int g = v0 * 32 + t;
    sx[t >> 5][t & 31] = (g < nV * 32) ? hseq[g] : 0.f;
  }
  __syncthreads();
  if (t < 128) {
    int n = t >> 5, j = t & 31;
    float s = sb1[j];
#pragma unroll
    for (int i = 0; i < 32; i++) s += sx[n][i] * sw1[i * 32 + j];
    st1[n][j] = fmaxf(s, 0.f);
  }
  __syncthreads();
  int n = t >> 6, j = t & 63;
  float s = sb2[j];
#pragma unroll
  for (int i = 0; i < 32; i++) s += st1[n][i] * sw2[i * 64 + j];
  if (v0 + n < nV) out[(size_t)(v0 + n) * 64 + j] = s;
}

extern "C" void kernel_launch(void* const* d_in, const int* in_sizes, int n_in,
                              void* d_out, int out_size, void* d_ws, size_t ws_size,
                              hipStream_t stream) {
  const float* node_feats = (const float*)d_in[0];
  const float* edge_feats = (const float*)d_in[1];
  const int* src = (const int*)d_in[2];
  const int* dst = (const int*)d_in[3];
  const float* proj_w1 = (const float*)d_in[4];
  const float* proj_b1 = (const float*)d_in[5];
  const float* proj_w2 = (const float*)d_in[6];
  const float* proj_b2 = (const float*)d_in[7];
  const float* e_w1 = (const float*)d_in[8];
  const float* e_b1 = (const float*)d_in[9];
  const float* e_w2 = (const float*)d_in[10];
  const float* e_b2 = (const float*)d_in[11];
  const float* conv_bias = (const float*)d_in[12];
  const float* gru_wih = (const float*)d_in[13];
  const float* gru_whh = (const float*)d_in[14];
  const float* gru_bih = (const float*)d_in[15];
  const float* gru_bhh = (const float*)d_in[16];
  const float* dec_w1 = (const float*)d_in[17];
  const float* dec_b1 = (const float*)d_in[18];
  const float* dec_w2 = (const float*)d_in[19];
  const float* dec_b2 = (const float*)d_in[20];
  float* out = (float*)d_out;

  const int nV = in_sizes[0] / 32;
  const int nE = in_sizes[2];
  // worst-case 16-padded idx space
  const int S = (nE + 15 * nV + 255) & ~255;

  // workspace carve-up (~206 MB worst case; proven-safe ~208)
  char* base = (char*)d_ws;
  size_t off = 0;
  auto carve = [&](size_t bytes) {
    void* r = base + off;
    off = (off + bytes + 255) & ~(size_t)255;
    return r;
  };
  ushort_t* aq_hi = (ushort_t*)carve((size_t)S * 128 * 2);
  ushort_t* aq_lo = (ushort_t*)carve((size_t)S * 128 * 2);
  float* hseq = (float*)carve((size_t)nV * 32 * 4);
  float* agg = (float*)carve((size_t)nV * 32 * 4);
  int* countsS = (int*)carve((size_t)nV * 4);
  int* rp16 = (int*)carve((size_t)(nV + 1) * 4);
  int* curS = (int*)carve((size_t)nV * 4);
  int* pose = (int*)carve((size_t)nE * 4);
  int* dstp = (int*)carve((size_t)S * 4);
  (void)ws_size;

  const int TB = 256;
  int gE = (nE + TB - 1) / TB;
  int g8 = (nV + 7) / 8;
  int g4 = (nV + 3) / 4;
  int gStep = (nV + NB - 1) / NB;

  // setup
  k_proj<<<g8, TB, 0, stream>>>(node_feats, proj_w1, proj_b1, proj_w2, proj_b2, hseq, nV);
  hipMemsetAsync(countsS, 0, (size_t)nV * 4, stream);
  hipMemsetAsync(dstp, 0xFF, (size_t)S * 4, stream);  // -1 sentinels
  hipMemsetAsync(agg, 0, (size_t)nV * 32 * 4, stream);  // covers 0xAA poison
  k_count<<<gE, TB, 0, stream>>>(src, countsS, nE);
  k_scan<<<1, 1024, 0, stream>>>(countsS, rp16, nV);
  k_copy<<<(nV + TB - 1) / TB, TB, 0, stream>>>(rp16, curS, nV);
  k_scatter<<<gE, TB, 0, stream>>>(src, dst, curS, pose, dstp, nE);
  k_edgebuild<<<(nE + 63) / 64, TB, 0, stream>>>(edge_feats, e_w1, e_b1, pose,
                                                 aq_hi, aq_lo, nE);

  // 6 message-passing steps (k_agru re-zeroes agg for the next step)
  for (int step = 0; step < 6; step++) {
    k_step<<<gStep, TB, 0, stream>>>(hseq, e_w2, e_b2, aq_hi, aq_lo, rp16, dstp,
                                     agg, nV);
    k_agru<<<g8, TB, 0, stream>>>(agg, conv_bias, gru_wih, gru_whh,
                                  gru_bih, gru_bhh, hseq, nV);
  }

  // decoder
  k_dec<<<g4, TB, 0, stream>>>(hseq, dec_w1, dec_b1, dec_w2, dec_b2, out, nV);
}

// Round 20
// 1440.843 us; speedup vs baseline: 1.0643x; 1.0643x over previous
//
#include <hip/hip_runtime.h>
#include <hip/hip_bf16.h>

// MPNN GNN: V=12500 (feat 32), E=200000 (feat 16), H=32, 6 steps.
// msg[e,o] = sum_k a[e,k]*T[src[e],k,o] + Tb[src[e],o],  a loop-invariant.
// R20: R18 base (best, 843us; R15/R17/R19 structural gambles all regressed)
// + A-fragment loads hoisted to chunk start (16x bf16x8, all kc), kc loop
// fully unrolled for static register indexing (rule: runtime-indexed reg
// arrays spill), __launch_bounds__(512,4) caps VGPR at 128. Attacks the
// exposed ~600cyc load->MFMA latency chain identified as the 70% stall
// (k_step: VALU 30%, Mfma 2.6%, HBM 12%, Occ 35% => latency-bound).
// Proven stack: split-bf16 3-GEMM MFMA (absmax 0.0156), kc-streamed 32KB T,
// j-split zero-redundancy w2 loads (R14 map), hidden LDS-write conflict,
// b128 h-reads (R18), dense edgebuild + pose scatter, one atomic per real
// (e,o), agg-rezero in k_agru.

#define NB 8   // src nodes per k_step block
#define TPW 2  // 16-edge tiles per wave per chunk
#define CAP (8 * TPW * 16)  // 256 padded slots per chunk

typedef __attribute__((ext_vector_type(8))) short bf16x8;
typedef __attribute__((ext_vector_type(4))) float f32x4;
typedef unsigned short ushort_t;

// ---------------- node projection: h = relu(nf@w1+b1)@w2+b2 ----------------
__global__ __launch_bounds__(256) void k_proj(
    const float* __restrict__ nf, const float* __restrict__ w1,
    const float* __restrict__ b1, const float* __restrict__ w2,
    const float* __restrict__ b2, float* __restrict__ hseq, int nV) {
  __shared__ float sw1[1024], sw2[1024], sb1[32], sb2[32];
  __shared__ float sx[8][32], st1[8][32];
  int t = threadIdx.x;
  int v0 = blockIdx.x * 8;
  for (int i = t; i < 1024; i += 256) { sw1[i] = w1[i]; sw2[i] = w2[i]; }
  if (t < 32) { sb1[t] = b1[t]; sb2[t] = b2[t]; }
  {
    int g = v0 * 32 + t;
    sx[t >> 5][t & 31] = (g < nV * 32) ? nf[g] : 0.f;
  }
  __syncthreads();
  int n = t >> 5, j = t & 31;
  float s = sb1[j];
#pragma unroll
  for (int i = 0; i < 32; i++) s += sx[n][i] * sw1[i * 32 + j];
  st1[n][j] = fmaxf(s, 0.f);
  __syncthreads();
  float h = sb2[j];
#pragma unroll
  for (int i = 0; i < 32; i++) h += st1[n][i] * sw2[i * 32 + j];
  if (v0 + n < nV) hseq[(size_t)(v0 + n) * 32 + j] = h;
}

// ---------------- CSR by src, padded to multiples of 16 --------------------
__global__ __launch_bounds__(256) void k_count(const int* __restrict__ key,
                                               int* __restrict__ counts, int nE) {
  int e = blockIdx.x * 256 + threadIdx.x;
  if (e < nE) atomicAdd(&counts[key[e]], 1);
}

__global__ __launch_bounds__(1024) void k_scan(const int* __restrict__ counts,
                                               int* __restrict__ row_ptr, int nV) {
  __shared__ int buf[1024];
  __shared__ int s_off;
  int t = threadIdx.x;
  if (t == 0) s_off = 0;
  __syncthreads();
  for (int base = 0; base < nV; base += 1024) {
    int x = (base + t < nV) ? ((counts[base + t] + 15) & ~15) : 0;  // pad to 16
    buf[t] = x;
    __syncthreads();
    for (int d = 1; d < 1024; d <<= 1) {
      int v2 = (t >= d) ? buf[t - d] : 0;
      __syncthreads();
      buf[t] += v2;
      __syncthreads();
    }
    int incl = buf[t];
    int off = s_off;
    __syncthreads();
    if (base + t < nV) row_ptr[base + t] = off + incl - x;  // exclusive
    if (t == 1023) s_off = off + incl;
    __syncthreads();
  }
  if (t == 0) row_ptr[nV] = s_off;
}

__global__ __launch_bounds__(256) void k_copy(const int* __restrict__ row_ptr,
                                              int* __restrict__ cursor, int nV) {
  int v = blockIdx.x * 256 + threadIdx.x;
  if (v < nV) cursor[v] = row_ptr[v];
}

// scatter: pose[e]=padded slot of edge e; dstp[slot]=dst (pads stay -1)
__global__ __launch_bounds__(256) void k_scatter(const int* __restrict__ key,
                                                 const int* __restrict__ dst,
                                                 int* __restrict__ cursor,
                                                 int* __restrict__ pose,
                                                 int* __restrict__ dstp, int nE) {
  int e = blockIdx.x * 256 + threadIdx.x;
  if (e < nE) {
    int p = atomicAdd(&cursor[key[e]], 1);
    pose[e] = p;
    dstp[p] = dst[e];
  }
}

// ------- edge MLP, dense over real edges -> split bf16 planes --------------
__global__ __launch_bounds__(256) void k_edgebuild(
    const float* __restrict__ ef, const float* __restrict__ w1,
    const float* __restrict__ b1, const int* __restrict__ pose,
    ushort_t* __restrict__ aq_hi, ushort_t* __restrict__ aq_lo, int nE) {
  __shared__ float sw1[16 * 128], sb1[128];
  __shared__ float sef[64][17];
  __shared__ int spos[64];
  int t = threadIdx.x;
  int e0 = blockIdx.x * 64;
  if (e0 >= nE) return;
  for (int i = t; i < 2048; i += 256) sw1[i] = w1[i];
  if (t < 128) sb1[t] = b1[t];
  for (int i = t; i < 1024; i += 256) {
    int g = e0 * 16 + i;
    sef[i >> 4][i & 15] = (g < nE * 16) ? ef[g] : 0.f;
  }
  if (t < 64) spos[t] = (e0 + t < nE) ? pose[e0 + t] : 0;
  __syncthreads();
  int c = t & 127;
#pragma unroll 1
  for (int it = 0; it < 32; ++it) {
    int el = it * 2 + (t >> 7);
    if (e0 + el < nE) {
      float s = sb1[c];
#pragma unroll
      for (int i = 0; i < 16; i++) s += sef[el][i] * sw1[i * 128 + c];
      s = fmaxf(s, 0.f);
      unsigned u = __float_as_uint(s);
      unsigned hb = u >> 16;
      float fh = __uint_as_float(hb << 16);
      unsigned lb = __float_as_uint(s - fh) >> 16;
      size_t p = (size_t)spos[el] * 128 + c;
      aq_hi[p] = (ushort_t)hb;
      aq_lo[p] = (ushort_t)lb;
    }
  }
}

// ---------------- per-step: kc-streamed T (j-split) + MFMA edges -----------
// LDS sTq (32 KB): quarter frags, ushort[(n*4 + h*2 + sp)*512 + l*8 + j]
//   = T[n][kc*32 + (l>>4)*8 + j][(l&15)+16h], sp: 0=hi 1=lo.
// T-phase map (R14/R16): jg=t>>7, th=(t>>6)&1, tl=t&63; b128 h-reads (R18).
// R20: A-frags for all 4 kc hoisted to chunk start; kc loop fully unrolled
// (static reg indices); __launch_bounds__(512,4) caps VGPR at 128.
__global__ __launch_bounds__(512, 4) void k_step(
    const float* __restrict__ hseq, const float* __restrict__ w2,
    const float* __restrict__ b2, const ushort_t* __restrict__ aq_hi,
    const ushort_t* __restrict__ aq_lo, const int* __restrict__ rp16,
    const int* __restrict__ dstp, float* __restrict__ agg, int nV) {
  __shared__ unsigned short sTq[16384];  // 32 KB
  __shared__ float sh[NB][32];     // [n][i] — Tb phase
  __shared__ float sh_t[32][NB];   // [i][n] — T phase (b128-readable)
  __shared__ float sTb[NB][32];
  __shared__ int s_rp[NB + 1];
  int t = threadIdx.x;
  int v0 = blockIdx.x * NB;
  if (t <= NB) {
    int v = v0 + t;
    if (v > nV) v = nV;
    s_rp[t] = rp16[v];
  }
  if (t < NB * 32) {
    int n = t >> 5, i = t & 31, v = v0 + n;
    float hv = (v < nV) ? hseq[(size_t)v * 32 + i] : 0.f;
    sh[n][i] = hv;
    sh_t[i][n] = hv;
  }
  __syncthreads();
  int beg = s_rp[0], end = s_rp[NB];
  if (beg == end) return;  // block-uniform

  if (t < NB * 32) {  // Tb[n][o] = sum_i h[n][i]*e_b2[i*32+o]
    int n = t >> 5, o = t & 31;
    float s = 0.f;
#pragma unroll
    for (int i = 0; i < 32; i++) s += sh[n][i] * b2[i * 32 + o];
    sTb[n][o] = s;
  }

  // thread constants — edge phase
  int wid = t >> 6, l = t & 63;
  int r = l & 15, kg = (l >> 4) << 3;
  // thread constants — T phase (j-split, R14 mapping)
  int jg = t >> 7;                  // 0..3: owns j = {2jg, 2jg+1}
  int th = (t >> 6) & 1;            // h half
  int tl = t & 63;                  // fragment lane
  int tc = (tl & 15) + th * 16;     // output column c
  int tkr = (tl >> 4) << 3;         // k row-group offset

  int nrun = 0;  // monotonic node cursor for this wave's tiles
  for (int cbase = beg; cbase < end; cbase += CAP) {
    int tn[TPW];
    bool live[TPW];
#pragma unroll
    for (int ti = 0; ti < TPW; ti++) {
      int idx16 = cbase + (wid * TPW + ti) * 16;
      live[ti] = (idx16 < end);
      if (live[ti]) {
        while (idx16 >= s_rp[nrun + 1]) nrun++;
        tn[ti] = nrun;
      } else
        tn[ti] = NB - 1;
    }
    // ---- hoisted A-frag loads: all kc, both tiles (latency hidden under T) -
    bf16x8 Ah[TPW][4], Al[TPW][4];
#pragma unroll
    for (int ti = 0; ti < TPW; ti++) {
      int idx16 = cbase + (wid * TPW + ti) * 16;
      if (live[ti]) {
        const ushort_t* ah = aq_hi + (size_t)(idx16 + r) * 128 + kg;
        const ushort_t* al = aq_lo + (size_t)(idx16 + r) * 128 + kg;
#pragma unroll
        for (int kc = 0; kc < 4; kc++) {
          Ah[ti][kc] = *(const bf16x8*)(ah + kc * 32);
          Al[ti][kc] = *(const bf16x8*)(al + kc * 32);
        }
      }
    }
    f32x4 acc[TPW][2];
#pragma unroll
    for (int ti = 0; ti < TPW; ti++)
#pragma unroll
      for (int hh = 0; hh < 2; hh++) acc[ti][hh] = (f32x4){0.f, 0.f, 0.f, 0.f};

#pragma unroll
    for (int kc = 0; kc < 4; kc++) {
      __syncthreads();  // protect sTq from previous phase's readers
      // ---- T-quarter, j-split: disjoint w2 loads; b128 h reads ----
      {
        int kbase = kc * 32 + tkr + 2 * jg;
        const float* wb = w2 + (size_t)kbase * 1024 + tc;  // + jj*1024 + i*32
        float a0[NB], a1[NB];
#pragma unroll
        for (int n = 0; n < NB; n++) { a0[n] = 0.f; a1[n] = 0.f; }
#pragma unroll 4
        for (int i = 0; i < 32; i++) {
          float w0 = wb[i * 32];
          float w1 = wb[1024 + i * 32];
          float4 sA = *(const float4*)&sh_t[i][0];
          float4 sB = *(const float4*)&sh_t[i][4];
          a0[0] += sA.x * w0; a1[0] += sA.x * w1;
          a0[1] += sA.y * w0; a1[1] += sA.y * w1;
          a0[2] += sA.z * w0; a1[2] += sA.z * w1;
          a0[3] += sA.w * w0; a1[3] += sA.w * w1;
          a0[4] += sB.x * w0; a1[4] += sB.x * w1;
          a0[5] += sB.y * w0; a1[5] += sB.y * w1;
          a0[6] += sB.z * w0; a1[6] += sB.z * w1;
          a0[7] += sB.w * w0; a1[7] += sB.w * w1;
        }
#pragma unroll
        for (int n = 0; n < NB; n++) {
          float x0 = a0[n], x1 = a1[n];
          unsigned h0 = __float_as_uint(x0) >> 16, h1 = __float_as_uint(x1) >> 16;
          unsigned l0 = __float_as_uint(x0 - __uint_as_float(h0 << 16)) >> 16;
          unsigned l1 = __float_as_uint(x1 - __uint_as_float(h1 << 16)) >> 16;
          int ub = ((n * 4 + th * 2) * 64 + tl) * 8 + 2 * jg;
          *(unsigned*)&sTq[ub] = h0 | (h1 << 16);        // sp=0 (hi)
          *(unsigned*)&sTq[ub + 512] = l0 | (l1 << 16);  // sp=1 (lo)
        }
      }
      __syncthreads();
      // ---- edge MFMA for this kc on TPW tiles (A-frags already in regs) ----
#pragma unroll
      for (int ti = 0; ti < TPW; ti++) {
        if (live[ti]) {
          int b = tn[ti] * 2048 + l * 8;
          bf16x8 B0h = *(const bf16x8*)&sTq[b];
          bf16x8 B0l = *(const bf16x8*)&sTq[b + 512];
          bf16x8 B1h = *(const bf16x8*)&sTq[b + 1024];
          bf16x8 B1l = *(const bf16x8*)&sTq[b + 1536];
          acc[ti][0] = __builtin_amdgcn_mfma_f32_16x16x32_bf16(Ah[ti][kc], B0h, acc[ti][0], 0, 0, 0);
          acc[ti][0] = __builtin_amdgcn_mfma_f32_16x16x32_bf16(Al[ti][kc], B0h, acc[ti][0], 0, 0, 0);
          acc[ti][0] = __builtin_amdgcn_mfma_f32_16x16x32_bf16(Ah[ti][kc], B0l, acc[ti][0], 0, 0, 0);
          acc[ti][1] = __builtin_amdgcn_mfma_f32_16x16x32_bf16(Ah[ti][kc], B1h, acc[ti][1], 0, 0, 0);
          acc[ti][1] = __builtin_amdgcn_mfma_f32_16x16x32_bf16(Al[ti][kc], B1h, acc[ti][1], 0, 0, 0);
          acc[ti][1] = __builtin_amdgcn_mfma_f32_16x16x32_bf16(Ah[ti][kc], B1l, acc[ti][1], 0, 0, 0);
        }
      }
    }
    // ---- flush: one atomic per real (e,o) ----
    int er = (l >> 4) << 2;
    int c = l & 15;
#pragma unroll
    for (int ti = 0; ti < TPW; ti++) {
      int idx16 = cbase + (wid * TPW + ti) * 16;
      if (live[ti]) {
#pragma unroll
        for (int j = 0; j < 4; j++) {
          int idx = idx16 + er + j;
          int d = dstp[idx];
          if (d >= 0) {
            atomicAdd(&agg[(size_t)d * 32 + c], acc[ti][0][j] + sTb[tn[ti]][c]);
            atomicAdd(&agg[(size_t)d * 32 + c + 16], acc[ti][1][j] + sTb[tn[ti]][c + 16]);
          }
        }
      }
    }
  }
}

// ------- fused agg-read + GRU + agg-rezero: block = 8 nodes x 32 o ---------
__global__ __launch_bounds__(256) void k_agru(
    float* __restrict__ agg, const float* __restrict__ cbias,
    const float* __restrict__ wih, const float* __restrict__ whh,
    const float* __restrict__ bih, const float* __restrict__ bhh,
    float* __restrict__ hseq, int nV) {
  __shared__ float swT[2][32 * 97];
  __shared__ float sb[2][96], scb[32];
  __shared__ float sx[8][32], shd[8][32];
  int t = threadIdx.x;
  int v0 = blockIdx.x * 8;
  for (int idx = t; idx < 3072; idx += 256) {
    int row = idx >> 5, i = idx & 31;
    swT[0][i * 97 + row] = wih[idx];
    swT[1][i * 97 + row] = whh[idx];
  }
  if (t < 96) { sb[0][t] = bih[t]; sb[1][t] = bhh[t]; }
  if (t < 32) scb[t] = cbias[t];
  {
    int n = t >> 5, v = v0 + n, j = t & 31;
    shd[n][j] = (v < nV) ? hseq[(size_t)v * 32 + j] : 0.f;
    float av = 0.f;
    if (v < nV) {
      av = agg[(size_t)v * 32 + j];
      agg[(size_t)v * 32 + j] = 0.f;  // re-zero for next step's atomics
    }
    sx[n][j] = (v < nV) ? fmaxf(av + cbias[j], 0.f) : 0.f;
  }
  __syncthreads();
  int n = t >> 5, o = t & 31;
  int v = v0 + n;
  if (v >= nV) return;
  float gir = sb[0][o], giz = sb[0][32 + o], gin = sb[0][64 + o];
  float ghr = sb[1][o], ghz = sb[1][32 + o], ghn = sb[1][64 + o];
#pragma unroll
  for (int i = 0; i < 32; i++) {
    float xi = sx[n][i], hi = shd[n][i];
    gir += xi * swT[0][i * 97 + o];
    giz += xi * swT[0][i * 97 + 32 + o];
    gin += xi * swT[0][i * 97 + 64 + o];
    ghr += hi * swT[1][i * 97 + o];
    ghz += hi * swT[1][i * 97 + 32 + o];
    ghn += hi * swT[1][i * 97 + 64 + o];
  }
  float r = 1.f / (1.f + __expf(-(gir + ghr)));
  float z = 1.f / (1.f + __expf(-(giz + ghz)));
  float ng = tanhf(gin + r * ghn);
  hseq[(size_t)v * 32 + o] = (1.f - z) * ng + z * shd[n][o];
}

// ---------------- decoder: out = relu(h@dw1+db1)@dw2+db2  (V x 64) ---------
__global__ __launch_bounds__(256) void k_dec(
    const float* __restrict__ hseq, const float* __restrict__ w1,
    const float* __restrict__ b1, const float* __restrict__ w2,
    const float* __restrict__ b2, float* __restrict__ out, int nV) {
  __shared__ float sw1[1024], sb1[32], sw2[2048], sb2[64];
  __shared__ float sx[4][32], st1[4][32];
  int t = threadIdx.x;
  int v0 = blockIdx.x * 4;
  for (int i = t; i < 1024; i += 256) sw1[i] = w1[i];
  for (int i = t; i < 2048; i += 256) sw2[i] = w2[i];
  if (t < 32) sb1[t] = b1[t];
  if (t < 64) sb2[t] = b2[t];
  if (t < 128) {
    int g = v0 * 32 + t;
    sx[t >> 5][t & 31] = (g < nV * 32) ? hseq[g] : 0.f;
  }
  __syncthreads();
  if (t < 128) {
    int n = t >> 5, j = t & 31;
    float s = sb1[j];
#pragma unroll
    for (int i = 0; i < 32; i++) s += sx[n][i] * sw1[i * 32 + j];
    st1[n][j] = fmaxf(s, 0.f);
  }
  __syncthreads();
  int n = t >> 6, j = t & 63;
  float s = sb2[j];
#pragma unroll
  for (int i = 0; i < 32; i++) s += st1[n][i] * sw2[i * 64 + j];
  if (v0 + n < nV) out[(size_t)(v0 + n) * 64 + j] = s;
}

extern "C" void kernel_launch(void* const* d_in, const int* in_sizes, int n_in,
                              void* d_out, int out_size, void* d_ws, size_t ws_size,
                              hipStream_t stream) {
  const float* node_feats = (const float*)d_in[0];
  const float* edge_feats = (const float*)d_in[1];
  const int* src = (const int*)d_in[2];
  const int* dst = (const int*)d_in[3];
  const float* proj_w1 = (const float*)d_in[4];
  const float* proj_b1 = (const float*)d_in[5];
  const float* proj_w2 = (const float*)d_in[6];
  const float* proj_b2 = (const float*)d_in[7];
  const float* e_w1 = (const float*)d_in[8];
  const float* e_b1 = (const float*)d_in[9];
  const float* e_w2 = (const float*)d_in[10];
  const float* e_b2 = (const float*)d_in[11];
  const float* conv_bias = (const float*)d_in[12];
  const float* gru_wih = (const float*)d_in[13];
  const float* gru_whh = (const float*)d_in[14];
  const float* gru_bih = (const float*)d_in[15];
  const float* gru_bhh = (const float*)d_in[16];
  const float* dec_w1 = (const float*)d_in[17];
  const float* dec_b1 = (const float*)d_in[18];
  const float* dec_w2 = (const float*)d_in[19];
  const float* dec_b2 = (const float*)d_in[20];
  float* out = (float*)d_out;

  const int nV = in_sizes[0] / 32;
  const int nE = in_sizes[2];
  // worst-case 16-padded idx space
  const int S = (nE + 15 * nV + 255) & ~255;

  // workspace carve-up (~206 MB worst case; proven-safe ~208)
  char* base = (char*)d_ws;
  size_t off = 0;
  auto carve = [&](size_t bytes) {
    void* r = base + off;
    off = (off + bytes + 255) & ~(size_t)255;
    return r;
  };
  ushort_t* aq_hi = (ushort_t*)carve((size_t)S * 128 * 2);
  ushort_t* aq_lo = (ushort_t*)carve((size_t)S * 128 * 2);
  float* hseq = (float*)carve((size_t)nV * 32 * 4);
  float* agg = (float*)carve((size_t)nV * 32 * 4);
  int* countsS = (int*)carve((size_t)nV * 4);
  int* rp16 = (int*)carve((size_t)(nV + 1) * 4);
  int* curS = (int*)carve((size_t)nV * 4);
  int* pose = (int*)carve((size_t)nE * 4);
  int* dstp = (int*)carve((size_t)S * 4);
  (void)ws_size;

  const int TB = 256;
  int gE = (nE + TB - 1) / TB;
  int g8 = (nV + 7) / 8;
  int g4 = (nV + 3) / 4;
  int gStep = (nV + NB - 1) / NB;

  // setup
  k_proj<<<g8, TB, 0, stream>>>(node_feats, proj_w1, proj_b1, proj_w2, proj_b2, hseq, nV);
  hipMemsetAsync(countsS, 0, (size_t)nV * 4, stream);
  hipMemsetAsync(dstp, 0xFF, (size_t)S * 4, stream);  // -1 sentinels
  hipMemsetAsync(agg, 0, (size_t)nV * 32 * 4, stream);  // covers 0xAA poison
  k_count<<<gE, TB, 0, stream>>>(src, countsS, nE);
  k_scan<<<1, 1024, 0, stream>>>(countsS, rp16, nV);
  k_copy<<<(nV + TB - 1) / TB, TB, 0, stream>>>(rp16, curS, nV);
  k_scatter<<<gE, TB, 0, stream>>>(src, dst, curS, pose, dstp, nE);
  k_edgebuild<<<(nE + 63) / 64, TB, 0, stream>>>(edge_feats, e_w1, e_b1, pose,
                                                 aq_hi, aq_lo, nE);

  // 6 message-passing steps (k_agru re-zeroes agg for the next step)
  for (int step = 0; step < 6; step++) {
    k_step<<<gStep, 512, 0, stream>>>(hseq, e_w2, e_b2, aq_hi, aq_lo, rp16, dstp,
                                      agg, nV);
    k_agru<<<g8, TB, 0, stream>>>(agg, conv_bias, gru_wih, gru_whh,
                                  gru_bih, gru_bhh, hseq, nV);
  }

  // decoder
  k_dec<<<g4, TB, 0, stream>>>(hseq, dec_w1, dec_b1, dec_w2, dec_b2, out, nV);
}

// Round 21
// 843.244 us; speedup vs baseline: 1.8186x; 1.7087x over previous
//
#include <hip/hip_runtime.h>
#include <hip/hip_bf16.h>

// MPNN GNN: V=12500 (feat 32), E=200000 (feat 16), H=32, 6 steps.
// msg[e,o] = sum_k a[e,k]*T[src[e],k,o] + Tb[src[e],o],  a loop-invariant.
// R21: FINAL — revert to R18 exactly (best: 843us, k_step 115us/step).
// Experiment ledger: R15 jg-remap (-28%: broke w2 quad-coalescing),
// R17 1024-thr (-34%: coarser packing), R19 256-thr (-82%: L3 thrash),
// R20 A-frag hoist (-71%: register spill, WRITE 25->58MB). R18's b128
// h-reads was the only win (+1.6%). Structure is latency-bound at its
// HIP-source floor: k_step VALU 30%, MfmaUtil 2.6%, HBM 12%, Occ 35%.
// Proven stack: split-bf16 3-GEMM MFMA (absmax 0.0156), kc-streamed 32KB T,
// j-split zero-redundancy w2 loads (R14 map: quads read consecutive bytes;
// stride-16B LDS write 8-way conflict measured fully-hidden), dense
// edgebuild + pose scatter, one atomic per real (e,o), agg-rezero in k_agru.

#define NB 8   // src nodes per k_step block
#define TPW 2  // 16-edge tiles per wave per chunk
#define CAP (8 * TPW * 16)  // 256 padded slots per chunk

typedef __attribute__((ext_vector_type(8))) short bf16x8;
typedef __attribute__((ext_vector_type(4))) float f32x4;
typedef unsigned short ushort_t;

// ---------------- node projection: h = relu(nf@w1+b1)@w2+b2 ----------------
__global__ __launch_bounds__(256) void k_proj(
    const float* __restrict__ nf, const float* __restrict__ w1,
    const float* __restrict__ b1, const float* __restrict__ w2,
    const float* __restrict__ b2, float* __restrict__ hseq, int nV) {
  __shared__ float sw1[1024], sw2[1024], sb1[32], sb2[32];
  __shared__ float sx[8][32], st1[8][32];
  int t = threadIdx.x;
  int v0 = blockIdx.x * 8;
  for (int i = t; i < 1024; i += 256) { sw1[i] = w1[i]; sw2[i] = w2[i]; }
  if (t < 32) { sb1[t] = b1[t]; sb2[t] = b2[t]; }
  {
    int g = v0 * 32 + t;
    sx[t >> 5][t & 31] = (g < nV * 32) ? nf[g] : 0.f;
  }
  __syncthreads();
  int n = t >> 5, j = t & 31;
  float s = sb1[j];
#pragma unroll
  for (int i = 0; i < 32; i++) s += sx[n][i] * sw1[i * 32 + j];
  st1[n][j] = fmaxf(s, 0.f);
  __syncthreads();
  float h = sb2[j];
#pragma unroll
  for (int i = 0; i < 32; i++) h += st1[n][i] * sw2[i * 32 + j];
  if (v0 + n < nV) hseq[(size_t)(v0 + n) * 32 + j] = h;
}

// ---------------- CSR by src, padded to multiples of 16 --------------------
__global__ __launch_bounds__(256) void k_count(const int* __restrict__ key,
                                               int* __restrict__ counts, int nE) {
  int e = blockIdx.x * 256 + threadIdx.x;
  if (e < nE) atomicAdd(&counts[key[e]], 1);
}

__global__ __launch_bounds__(1024) void k_scan(const int* __restrict__ counts,
                                               int* __restrict__ row_ptr, int nV) {
  __shared__ int buf[1024];
  __shared__ int s_off;
  int t = threadIdx.x;
  if (t == 0) s_off = 0;
  __syncthreads();
  for (int base = 0; base < nV; base += 1024) {
    int x = (base + t < nV) ? ((counts[base + t] + 15) & ~15) : 0;  // pad to 16
    buf[t] = x;
    __syncthreads();
    for (int d = 1; d < 1024; d <<= 1) {
      int v2 = (t >= d) ? buf[t - d] : 0;
      __syncthreads();
      buf[t] += v2;
      __syncthreads();
    }
    int incl = buf[t];
    int off = s_off;
    __syncthreads();
    if (base + t < nV) row_ptr[base + t] = off + incl - x;  // exclusive
    if (t == 1023) s_off = off + incl;
    __syncthreads();
  }
  if (t == 0) row_ptr[nV] = s_off;
}

__global__ __launch_bounds__(256) void k_copy(const int* __restrict__ row_ptr,
                                              int* __restrict__ cursor, int nV) {
  int v = blockIdx.x * 256 + threadIdx.x;
  if (v < nV) cursor[v] = row_ptr[v];
}

// scatter: pose[e]=padded slot of edge e; dstp[slot]=dst (pads stay -1)
__global__ __launch_bounds__(256) void k_scatter(const int* __restrict__ key,
                                                 const int* __restrict__ dst,
                                                 int* __restrict__ cursor,
                                                 int* __restrict__ pose,
                                                 int* __restrict__ dstp, int nE) {
  int e = blockIdx.x * 256 + threadIdx.x;
  if (e < nE) {
    int p = atomicAdd(&cursor[key[e]], 1);
    pose[e] = p;
    dstp[p] = dst[e];
  }
}

// ------- edge MLP, dense over real edges -> split bf16 planes --------------
__global__ __launch_bounds__(256) void k_edgebuild(
    const float* __restrict__ ef, const float* __restrict__ w1,
    const float* __restrict__ b1, const int* __restrict__ pose,
    ushort_t* __restrict__ aq_hi, ushort_t* __restrict__ aq_lo, int nE) {
  __shared__ float sw1[16 * 128], sb1[128];
  __shared__ float sef[64][17];
  __shared__ int spos[64];
  int t = threadIdx.x;
  int e0 = blockIdx.x * 64;
  if (e0 >= nE) return;
  for (int i = t; i < 2048; i += 256) sw1[i] = w1[i];
  if (t < 128) sb1[t] = b1[t];
  for (int i = t; i < 1024; i += 256) {
    int g = e0 * 16 + i;
    sef[i >> 4][i & 15] = (g < nE * 16) ? ef[g] : 0.f;
  }
  if (t < 64) spos[t] = (e0 + t < nE) ? pose[e0 + t] : 0;
  __syncthreads();
  int c = t & 127;
#pragma unroll 1
  for (int it = 0; it < 32; ++it) {
    int el = it * 2 + (t >> 7);
    if (e0 + el < nE) {
      float s = sb1[c];
#pragma unroll
      for (int i = 0; i < 16; i++) s += sef[el][i] * sw1[i * 128 + c];
      s = fmaxf(s, 0.f);
      unsigned u = __float_as_uint(s);
      unsigned hb = u >> 16;
      float fh = __uint_as_float(hb << 16);
      unsigned lb = __float_as_uint(s - fh) >> 16;
      size_t p = (size_t)spos[el] * 128 + c;
      aq_hi[p] = (ushort_t)hb;
      aq_lo[p] = (ushort_t)lb;
    }
  }
}

// ---------------- per-step: kc-streamed T (j-split) + MFMA edges -----------
// LDS sTq (32 KB): quarter frags, ushort[(n*4 + h*2 + sp)*512 + l*8 + j]
//   = T[n][kc*32 + (l>>4)*8 + j][(l&15)+16h], sp: 0=hi 1=lo.
// T-phase thread map (R14/R16 proven): jg=t>>7, th=(t>>6)&1, tl=t&63.
// R18: h read via transposed sh_t[32][8] -> 2x ds_read_b128 per i.
__global__ __launch_bounds__(512) void k_step(
    const float* __restrict__ hseq, const float* __restrict__ w2,
    const float* __restrict__ b2, const ushort_t* __restrict__ aq_hi,
    const ushort_t* __restrict__ aq_lo, const int* __restrict__ rp16,
    const int* __restrict__ dstp, float* __restrict__ agg, int nV) {
  __shared__ unsigned short sTq[16384];  // 32 KB
  __shared__ float sh[NB][32];     // [n][i] — Tb phase
  __shared__ float sh_t[32][NB];   // [i][n] — T phase (b128-readable)
  __shared__ float sTb[NB][32];
  __shared__ int s_rp[NB + 1];
  int t = threadIdx.x;
  int v0 = blockIdx.x * NB;
  if (t <= NB) {
    int v = v0 + t;
    if (v > nV) v = nV;
    s_rp[t] = rp16[v];
  }
  if (t < NB * 32) {
    int n = t >> 5, i = t & 31, v = v0 + n;
    float hv = (v < nV) ? hseq[(size_t)v * 32 + i] : 0.f;
    sh[n][i] = hv;
    sh_t[i][n] = hv;
  }
  __syncthreads();
  int beg = s_rp[0], end = s_rp[NB];
  if (beg == end) return;  // block-uniform

  if (t < NB * 32) {  // Tb[n][o] = sum_i h[n][i]*e_b2[i*32+o]
    int n = t >> 5, o = t & 31;
    float s = 0.f;
#pragma unroll
    for (int i = 0; i < 32; i++) s += sh[n][i] * b2[i * 32 + o];
    sTb[n][o] = s;
  }

  // thread constants — edge phase
  int wid = t >> 6, l = t & 63;
  int r = l & 15, kg = (l >> 4) << 3;
  // thread constants — T phase (j-split, R14 mapping)
  int jg = t >> 7;                  // 0..3: owns j = {2jg, 2jg+1}
  int th = (t >> 6) & 1;            // h half
  int tl = t & 63;                  // fragment lane
  int tc = (tl & 15) + th * 16;     // output column c
  int tkr = (tl >> 4) << 3;         // k row-group offset

  int nrun = 0;  // monotonic node cursor for this wave's tiles
  for (int cbase = beg; cbase < end; cbase += CAP) {
    int tn[TPW];
#pragma unroll
    for (int ti = 0; ti < TPW; ti++) {
      int idx16 = cbase + (wid * TPW + ti) * 16;
      if (idx16 < end) {
        while (idx16 >= s_rp[nrun + 1]) nrun++;
        tn[ti] = nrun;
      } else
        tn[ti] = NB - 1;
    }
    f32x4 acc[TPW][2];
#pragma unroll
    for (int ti = 0; ti < TPW; ti++)
#pragma unroll
      for (int hh = 0; hh < 2; hh++) acc[ti][hh] = (f32x4){0.f, 0.f, 0.f, 0.f};

#pragma unroll 1
    for (int kc = 0; kc < 4; kc++) {
      __syncthreads();  // protect sTq from previous phase's readers
      // ---- T-quarter, j-split: disjoint w2 loads; b128 h reads ----
      {
        int kbase = kc * 32 + tkr + 2 * jg;
        const float* wb = w2 + (size_t)kbase * 1024 + tc;  // + jj*1024 + i*32
        float a0[NB], a1[NB];
#pragma unroll
        for (int n = 0; n < NB; n++) { a0[n] = 0.f; a1[n] = 0.f; }
#pragma unroll 4
        for (int i = 0; i < 32; i++) {
          float w0 = wb[i * 32];
          float w1 = wb[1024 + i * 32];
          float4 sA = *(const float4*)&sh_t[i][0];
          float4 sB = *(const float4*)&sh_t[i][4];
          a0[0] += sA.x * w0; a1[0] += sA.x * w1;
          a0[1] += sA.y * w0; a1[1] += sA.y * w1;
          a0[2] += sA.z * w0; a1[2] += sA.z * w1;
          a0[3] += sA.w * w0; a1[3] += sA.w * w1;
          a0[4] += sB.x * w0; a1[4] += sB.x * w1;
          a0[5] += sB.y * w0; a1[5] += sB.y * w1;
          a0[6] += sB.z * w0; a1[6] += sB.z * w1;
          a0[7] += sB.w * w0; a1[7] += sB.w * w1;
        }
#pragma unroll
        for (int n = 0; n < NB; n++) {
          float x0 = a0[n], x1 = a1[n];
          unsigned h0 = __float_as_uint(x0) >> 16, h1 = __float_as_uint(x1) >> 16;
          unsigned l0 = __float_as_uint(x0 - __uint_as_float(h0 << 16)) >> 16;
          unsigned l1 = __float_as_uint(x1 - __uint_as_float(h1 << 16)) >> 16;
          int ub = ((n * 4 + th * 2) * 64 + tl) * 8 + 2 * jg;
          *(unsigned*)&sTq[ub] = h0 | (h1 << 16);        // sp=0 (hi)
          *(unsigned*)&sTq[ub + 512] = l0 | (l1 << 16);  // sp=1 (lo)
        }
      }
      __syncthreads();
      // ---- edge MFMA for this kc on TPW tiles ----
#pragma unroll
      for (int ti = 0; ti < TPW; ti++) {
        int idx16 = cbase + (wid * TPW + ti) * 16;
        if (idx16 < end) {
          const ushort_t* ah = aq_hi + (size_t)(idx16 + r) * 128 + kc * 32 + kg;
          const ushort_t* al = aq_lo + (size_t)(idx16 + r) * 128 + kc * 32 + kg;
          bf16x8 Ah = *(const bf16x8*)ah;
          bf16x8 Al = *(const bf16x8*)al;
          int b = tn[ti] * 2048 + l * 8;
          bf16x8 B0h = *(const bf16x8*)&sTq[b];
          bf16x8 B0l = *(const bf16x8*)&sTq[b + 512];
          bf16x8 B1h = *(const bf16x8*)&sTq[b + 1024];
          bf16x8 B1l = *(const bf16x8*)&sTq[b + 1536];
          acc[ti][0] = __builtin_amdgcn_mfma_f32_16x16x32_bf16(Ah, B0h, acc[ti][0], 0, 0, 0);
          acc[ti][0] = __builtin_amdgcn_mfma_f32_16x16x32_bf16(Al, B0h, acc[ti][0], 0, 0, 0);
          acc[ti][0] = __builtin_amdgcn_mfma_f32_16x16x32_bf16(Ah, B0l, acc[ti][0], 0, 0, 0);
          acc[ti][1] = __builtin_amdgcn_mfma_f32_16x16x32_bf16(Ah, B1h, acc[ti][1], 0, 0, 0);
          acc[ti][1] = __builtin_amdgcn_mfma_f32_16x16x32_bf16(Al, B1h, acc[ti][1], 0, 0, 0);
          acc[ti][1] = __builtin_amdgcn_mfma_f32_16x16x32_bf16(Ah, B1l, acc[ti][1], 0, 0, 0);
        }
      }
    }
    // ---- flush: one atomic per real (e,o) ----
    int er = (l >> 4) << 2;
    int c = l & 15;
#pragma unroll
    for (int ti = 0; ti < TPW; ti++) {
      int idx16 = cbase + (wid * TPW + ti) * 16;
      if (idx16 < end) {
#pragma unroll
        for (int j = 0; j < 4; j++) {
          int idx = idx16 + er + j;
          int d = dstp[idx];
          if (d >= 0) {
            atomicAdd(&agg[(size_t)d * 32 + c], acc[ti][0][j] + sTb[tn[ti]][c]);
            atomicAdd(&agg[(size_t)d * 32 + c + 16], acc[ti][1][j] + sTb[tn[ti]][c + 16]);
          }
        }
      }
    }
  }
}

// ------- fused agg-read + GRU + agg-rezero: block = 8 nodes x 32 o ---------
__global__ __launch_bounds__(256) void k_agru(
    float* __restrict__ agg, const float* __restrict__ cbias,
    const float* __restrict__ wih, const float* __restrict__ whh,
    const float* __restrict__ bih, const float* __restrict__ bhh,
    float* __restrict__ hseq, int nV) {
  __shared__ float swT[2][32 * 97];
  __shared__ float sb[2][96], scb[32];
  __shared__ float sx[8][32], shd[8][32];
  int t = threadIdx.x;
  int v0 = blockIdx.x * 8;
  for (int idx = t; idx < 3072; idx += 256) {
    int row = idx >> 5, i = idx & 31;
    swT[0][i * 97 + row] = wih[idx];
    swT[1][i * 97 + row] = whh[idx];
  }
  if (t < 96) { sb[0][t] = bih[t]; sb[1][t] = bhh[t]; }
  if (t < 32) scb[t] = cbias[t];
  {
    int n = t >> 5, v = v0 + n, j = t & 31;
    shd[n][j] = (v < nV) ? hseq[(size_t)v * 32 + j] : 0.f;
    float av = 0.f;
    if (v < nV) {
      av = agg[(size_t)v * 32 + j];
      agg[(size_t)v * 32 + j] = 0.f;  // re-zero for next step's atomics
    }
    sx[n][j] = (v < nV) ? fmaxf(av + cbias[j], 0.f) : 0.f;
  }
  __syncthreads();
  int n = t >> 5, o = t & 31;
  int v = v0 + n;
  if (v >= nV) return;
  float gir = sb[0][o], giz = sb[0][32 + o], gin = sb[0][64 + o];
  float ghr = sb[1][o], ghz = sb[1][32 + o], ghn = sb[1][64 + o];
#pragma unroll
  for (int i = 0; i < 32; i++) {
    float xi = sx[n][i], hi = shd[n][i];
    gir += xi * swT[0][i * 97 + o];
    giz += xi * swT[0][i * 97 + 32 + o];
    gin += xi * swT[0][i * 97 + 64 + o];
    ghr += hi * swT[1][i * 97 + o];
    ghz += hi * swT[1][i * 97 + 32 + o];
    ghn += hi * swT[1][i * 97 + 64 + o];
  }
  float r = 1.f / (1.f + __expf(-(gir + ghr)));
  float z = 1.f / (1.f + __expf(-(giz + ghz)));
  float ng = tanhf(gin + r * ghn);
  hseq[(size_t)v * 32 + o] = (1.f - z) * ng + z * shd[n][o];
}

// ---------------- decoder: out = relu(h@dw1+db1)@dw2+db2  (V x 64) ---------
__global__ __launch_bounds__(256) void k_dec(
    const float* __restrict__ hseq, const float* __restrict__ w1,
    const float* __restrict__ b1, const float* __restrict__ w2,
    const float* __restrict__ b2, float* __restrict__ out, int nV) {
  __shared__ float sw1[1024], sb1[32], sw2[2048], sb2[64];
  __shared__ float sx[4][32], st1[4][32];
  int t = threadIdx.x;
  int v0 = blockIdx.x * 4;
  for (int i = t; i < 1024; i += 256) sw1[i] = w1[i];
  for (int i = t; i < 2048; i += 256) sw2[i] = w2[i];
  if (t < 32) sb1[t] = b1[t];
  if (t < 64) sb2[t] = b2[t];
  if (t < 128) {
    int g = v0 * 32 + t;
    sx[t >> 5][t & 31] = (g < nV * 32) ? hseq[g] : 0.f;
  }
  __syncthreads();
  if (t < 128) {
    int n = t >> 5, j = t & 31;
    float s = sb1[j];
#pragma unroll
    for (int i = 0; i < 32; i++) s += sx[n][i] * sw1[i * 32 + j];
    st1[n][j] = fmaxf(s, 0.f);
  }
  __syncthreads();
  int n = t >> 6, j = t & 63;
  float s = sb2[j];
#pragma unroll
  for (int i = 0; i < 32; i++) s += st1[n][i] * sw2[i * 64 + j];
  if (v0 + n < nV) out[(size_t)(v0 + n) * 64 + j] = s;
}

extern "C" void kernel_launch(void* const* d_in, const int* in_sizes, int n_in,
                              void* d_out, int out_size, void* d_ws, size_t ws_size,
                              hipStream_t stream) {
  const float* node_feats = (const float*)d_in[0];
  const float* edge_feats = (const float*)d_in[1];
  const int* src = (const int*)d_in[2];
  const int* dst = (const int*)d_in[3];
  const float* proj_w1 = (const float*)d_in[4];
  const float* proj_b1 = (const float*)d_in[5];
  const float* proj_w2 = (const float*)d_in[6];
  const float* proj_b2 = (const float*)d_in[7];
  const float* e_w1 = (const float*)d_in[8];
  const float* e_b1 = (const float*)d_in[9];
  const float* e_w2 = (const float*)d_in[10];
  const float* e_b2 = (const float*)d_in[11];
  const float* conv_bias = (const float*)d_in[12];
  const float* gru_wih = (const float*)d_in[13];
  const float* gru_whh = (const float*)d_in[14];
  const float* gru_bih = (const float*)d_in[15];
  const float* gru_bhh = (const float*)d_in[16];
  const float* dec_w1 = (const float*)d_in[17];
  const float* dec_b1 = (const float*)d_in[18];
  const float* dec_w2 = (const float*)d_in[19];
  const float* dec_b2 = (const float*)d_in[20];
  float* out = (float*)d_out;

  const int nV = in_sizes[0] / 32;
  const int nE = in_sizes[2];
  // worst-case 16-padded idx space
  const int S = (nE + 15 * nV + 255) & ~255;

  // workspace carve-up (~206 MB worst case; proven-safe ~208)
  char* base = (char*)d_ws;
  size_t off = 0;
  auto carve = [&](size_t bytes) {
    void* r = base + off;
    off = (off + bytes + 255) & ~(size_t)255;
    return r;
  };
  ushort_t* aq_hi = (ushort_t*)carve((size_t)S * 128 * 2);
  ushort_t* aq_lo = (ushort_t*)carve((size_t)S * 128 * 2);
  float* hseq = (float*)carve((size_t)nV * 32 * 4);
  float* agg = (float*)carve((size_t)nV * 32 * 4);
  int* countsS = (int*)carve((size_t)nV * 4);
  int* rp16 = (int*)carve((size_t)(nV + 1) * 4);
  int* curS = (int*)carve((size_t)nV * 4);
  int* pose = (int*)carve((size_t)nE * 4);
  int* dstp = (int*)carve((size_t)S * 4);
  (void)ws_size;

  const int TB = 256;
  int gE = (nE + TB - 1) / TB;
  int g8 = (nV + 7) / 8;
  int g4 = (nV + 3) / 4;
  int gStep = (nV + NB - 1) / NB;

  // setup
  k_proj<<<g8, TB, 0, stream>>>(node_feats, proj_w1, proj_b1, proj_w2, proj_b2, hseq, nV);
  hipMemsetAsync(countsS, 0, (size_t)nV * 4, stream);
  hipMemsetAsync(dstp, 0xFF, (size_t)S * 4, stream);  // -1 sentinels
  hipMemsetAsync(agg, 0, (size_t)nV * 32 * 4, stream);  // covers 0xAA poison
  k_count<<<gE, TB, 0, stream>>>(src, countsS, nE);
  k_scan<<<1, 1024, 0, stream>>>(countsS, rp16, nV);
  k_copy<<<(nV + TB - 1) / TB, TB, 0, stream>>>(rp16, curS, nV);
  k_scatter<<<gE, TB, 0, stream>>>(src, dst, curS, pose, dstp, nE);
  k_edgebuild<<<(nE + 63) / 64, TB, 0, stream>>>(edge_feats, e_w1, e_b1, pose,
                                                 aq_hi, aq_lo, nE);

  // 6 message-passing steps (k_agru re-zeroes agg for the next step)
  for (int step = 0; step < 6; step++) {
    k_step<<<gStep, 512, 0, stream>>>(hseq, e_w2, e_b2, aq_hi, aq_lo, rp16, dstp,
                                      agg, nV);
    k_agru<<<g8, TB, 0, stream>>>(agg, conv_bias, gru_wih, gru_whh,
                                  gru_bih, gru_bhh, hseq, nV);
  }

  // decoder
  k_dec<<<g4, TB, 0, stream>>>(hseq, dec_w1, dec_b1, dec_w2, dec_b2, out, nV);
}

// Round 22
// 827.220 us; speedup vs baseline: 1.8538x; 1.0194x over previous
//
#include <hip/hip_runtime.h>
#include <hip/hip_bf16.h>

// MPNN GNN: V=12500 (feat 32), E=200000 (feat 16), H=32, 6 steps.
// msg[e,o] = sum_k a[e,k]*T[src[e],k,o] + Tb[src[e],o],  a loop-invariant.
// R22: R18/R21 base (proven 843us) + DOUBLE-BUFFERED sTq (2x32KB=64KB):
// one barrier per kc instead of two (8->4 per chunk). Safety: barrier(kc)
// globally orders MFMA(kc-1) reads of buf[(kc-1)&1] before T-write(kc+1)
// to that buffer. MFMA(kc) now overlaps T-write(kc+1)'s w2 load issue.
// LDS 36->68KB: 2 blk/CU x 8 waves = 16 waves/CU (> current ~11).
// Ledger: R15 jg-remap(-), R17 1024thr(-), R19 256thr(-), R20 hoist(-spill),
// R18 b128-h(+). Proven stack: split-bf16 3-GEMM MFMA (absmax 0.0156),
// kc-streamed T, j-split zero-redundancy w2 loads (R14 map), hidden LDS
// write conflict, dense edgebuild + pose scatter, one atomic per real (e,o),
// agg-rezero in k_agru.

#define NB 8   // src nodes per k_step block
#define TPW 2  // 16-edge tiles per wave per chunk
#define CAP (8 * TPW * 16)  // 256 padded slots per chunk

typedef __attribute__((ext_vector_type(8))) short bf16x8;
typedef __attribute__((ext_vector_type(4))) float f32x4;
typedef unsigned short ushort_t;

// ---------------- node projection: h = relu(nf@w1+b1)@w2+b2 ----------------
__global__ __launch_bounds__(256) void k_proj(
    const float* __restrict__ nf, const float* __restrict__ w1,
    const float* __restrict__ b1, const float* __restrict__ w2,
    const float* __restrict__ b2, float* __restrict__ hseq, int nV) {
  __shared__ float sw1[1024], sw2[1024], sb1[32], sb2[32];
  __shared__ float sx[8][32], st1[8][32];
  int t = threadIdx.x;
  int v0 = blockIdx.x * 8;
  for (int i = t; i < 1024; i += 256) { sw1[i] = w1[i]; sw2[i] = w2[i]; }
  if (t < 32) { sb1[t] = b1[t]; sb2[t] = b2[t]; }
  {
    int g = v0 * 32 + t;
    sx[t >> 5][t & 31] = (g < nV * 32) ? nf[g] : 0.f;
  }
  __syncthreads();
  int n = t >> 5, j = t & 31;
  float s = sb1[j];
#pragma unroll
  for (int i = 0; i < 32; i++) s += sx[n][i] * sw1[i * 32 + j];
  st1[n][j] = fmaxf(s, 0.f);
  __syncthreads();
  float h = sb2[j];
#pragma unroll
  for (int i = 0; i < 32; i++) h += st1[n][i] * sw2[i * 32 + j];
  if (v0 + n < nV) hseq[(size_t)(v0 + n) * 32 + j] = h;
}

// ---------------- CSR by src, padded to multiples of 16 --------------------
__global__ __launch_bounds__(256) void k_count(const int* __restrict__ key,
                                               int* __restrict__ counts, int nE) {
  int e = blockIdx.x * 256 + threadIdx.x;
  if (e < nE) atomicAdd(&counts[key[e]], 1);
}

__global__ __launch_bounds__(1024) void k_scan(const int* __restrict__ counts,
                                               int* __restrict__ row_ptr, int nV) {
  __shared__ int buf[1024];
  __shared__ int s_off;
  int t = threadIdx.x;
  if (t == 0) s_off = 0;
  __syncthreads();
  for (int base = 0; base < nV; base += 1024) {
    int x = (base + t < nV) ? ((counts[base + t] + 15) & ~15) : 0;  // pad to 16
    buf[t] = x;
    __syncthreads();
    for (int d = 1; d < 1024; d <<= 1) {
      int v2 = (t >= d) ? buf[t - d] : 0;
      __syncthreads();
      buf[t] += v2;
      __syncthreads();
    }
    int incl = buf[t];
    int off = s_off;
    __syncthreads();
    if (base + t < nV) row_ptr[base + t] = off + incl - x;  // exclusive
    if (t == 1023) s_off = off + incl;
    __syncthreads();
  }
  if (t == 0) row_ptr[nV] = s_off;
}

__global__ __launch_bounds__(256) void k_copy(const int* __restrict__ row_ptr,
                                              int* __restrict__ cursor, int nV) {
  int v = blockIdx.x * 256 + threadIdx.x;
  if (v < nV) cursor[v] = row_ptr[v];
}

// scatter: pose[e]=padded slot of edge e; dstp[slot]=dst (pads stay -1)
__global__ __launch_bounds__(256) void k_scatter(const int* __restrict__ key,
                                                 const int* __restrict__ dst,
                                                 int* __restrict__ cursor,
                                                 int* __restrict__ pose,
                                                 int* __restrict__ dstp, int nE) {
  int e = blockIdx.x * 256 + threadIdx.x;
  if (e < nE) {
    int p = atomicAdd(&cursor[key[e]], 1);
    pose[e] = p;
    dstp[p] = dst[e];
  }
}

// ------- edge MLP, dense over real edges -> split bf16 planes --------------
__global__ __launch_bounds__(256) void k_edgebuild(
    const float* __restrict__ ef, const float* __restrict__ w1,
    const float* __restrict__ b1, const int* __restrict__ pose,
    ushort_t* __restrict__ aq_hi, ushort_t* __restrict__ aq_lo, int nE) {
  __shared__ float sw1[16 * 128], sb1[128];
  __shared__ float sef[64][17];
  __shared__ int spos[64];
  int t = threadIdx.x;
  int e0 = blockIdx.x * 64;
  if (e0 >= nE) return;
  for (int i = t; i < 2048; i += 256) sw1[i] = w1[i];
  if (t < 128) sb1[t] = b1[t];
  for (int i = t; i < 1024; i += 256) {
    int g = e0 * 16 + i;
    sef[i >> 4][i & 15] = (g < nE * 16) ? ef[g] : 0.f;
  }
  if (t < 64) spos[t] = (e0 + t < nE) ? pose[e0 + t] : 0;
  __syncthreads();
  int c = t & 127;
#pragma unroll 1
  for (int it = 0; it < 32; ++it) {
    int el = it * 2 + (t >> 7);
    if (e0 + el < nE) {
      float s = sb1[c];
#pragma unroll
      for (int i = 0; i < 16; i++) s += sef[el][i] * sw1[i * 128 + c];
      s = fmaxf(s, 0.f);
      unsigned u = __float_as_uint(s);
      unsigned hb = u >> 16;
      float fh = __uint_as_float(hb << 16);
      unsigned lb = __float_as_uint(s - fh) >> 16;
      size_t p = (size_t)spos[el] * 128 + c;
      aq_hi[p] = (ushort_t)hb;
      aq_lo[p] = (ushort_t)lb;
    }
  }
}

// ---------------- per-step: kc-streamed T (j-split) + MFMA edges -----------
// Double-buffered LDS sTq (2 x 32 KB): buffer kc&1 holds quarter frags,
// ushort[(n*4 + h*2 + sp)*512 + l*8 + j] = T[n][kc*32 + (l>>4)*8 + j]
// [(l&15)+16h], sp: 0=hi 1=lo. ONE barrier per kc (between T-write and
// MFMA-read of the same buffer); write(kc+1) vs read(kc) touch different
// buffers; read(kc-1) vs write(kc+1) ordered by barrier(kc).
// T-phase map (R14/R16): jg=t>>7, th=(t>>6)&1, tl=t&63; b128 h-reads (R18).
__global__ __launch_bounds__(512) void k_step(
    const float* __restrict__ hseq, const float* __restrict__ w2,
    const float* __restrict__ b2, const ushort_t* __restrict__ aq_hi,
    const ushort_t* __restrict__ aq_lo, const int* __restrict__ rp16,
    const int* __restrict__ dstp, float* __restrict__ agg, int nV) {
  __shared__ unsigned short sTq[32768];  // 64 KB, two 16384-ushort buffers
  __shared__ float sh[NB][32];     // [n][i] — Tb phase
  __shared__ float sh_t[32][NB];   // [i][n] — T phase (b128-readable)
  __shared__ float sTb[NB][32];
  __shared__ int s_rp[NB + 1];
  int t = threadIdx.x;
  int v0 = blockIdx.x * NB;
  if (t <= NB) {
    int v = v0 + t;
    if (v > nV) v = nV;
    s_rp[t] = rp16[v];
  }
  if (t < NB * 32) {
    int n = t >> 5, i = t & 31, v = v0 + n;
    float hv = (v < nV) ? hseq[(size_t)v * 32 + i] : 0.f;
    sh[n][i] = hv;
    sh_t[i][n] = hv;
  }
  __syncthreads();
  int beg = s_rp[0], end = s_rp[NB];
  if (beg == end) return;  // block-uniform

  if (t < NB * 32) {  // Tb[n][o] = sum_i h[n][i]*e_b2[i*32+o]
    int n = t >> 5, o = t & 31;
    float s = 0.f;
#pragma unroll
    for (int i = 0; i < 32; i++) s += sh[n][i] * b2[i * 32 + o];
    sTb[n][o] = s;
  }

  // thread constants — edge phase
  int wid = t >> 6, l = t & 63;
  int r = l & 15, kg = (l >> 4) << 3;
  // thread constants — T phase (j-split, R14 mapping)
  int jg = t >> 7;                  // 0..3: owns j = {2jg, 2jg+1}
  int th = (t >> 6) & 1;            // h half
  int tl = t & 63;                  // fragment lane
  int tc = (tl & 15) + th * 16;     // output column c
  int tkr = (tl >> 4) << 3;         // k row-group offset

  int nrun = 0;  // monotonic node cursor for this wave's tiles
  for (int cbase = beg; cbase < end; cbase += CAP) {
    int tn[TPW];
#pragma unroll
    for (int ti = 0; ti < TPW; ti++) {
      int idx16 = cbase + (wid * TPW + ti) * 16;
      if (idx16 < end) {
        while (idx16 >= s_rp[nrun + 1]) nrun++;
        tn[ti] = nrun;
      } else
        tn[ti] = NB - 1;
    }
    f32x4 acc[TPW][2];
#pragma unroll
    for (int ti = 0; ti < TPW; ti++)
#pragma unroll
      for (int hh = 0; hh < 2; hh++) acc[ti][hh] = (f32x4){0.f, 0.f, 0.f, 0.f};

#pragma unroll 1
    for (int kc = 0; kc < 4; kc++) {
      int bufo = (kc & 1) << 14;  // 0 or 16384 ushorts
      // ---- T-quarter, j-split: disjoint w2 loads; b128 h reads ----
      {
        int kbase = kc * 32 + tkr + 2 * jg;
        const float* wb = w2 + (size_t)kbase * 1024 + tc;  // + jj*1024 + i*32
        float a0[NB], a1[NB];
#pragma unroll
        for (int n = 0; n < NB; n++) { a0[n] = 0.f; a1[n] = 0.f; }
#pragma unroll 4
        for (int i = 0; i < 32; i++) {
          float w0 = wb[i * 32];
          float w1 = wb[1024 + i * 32];
          float4 sA = *(const float4*)&sh_t[i][0];
          float4 sB = *(const float4*)&sh_t[i][4];
          a0[0] += sA.x * w0; a1[0] += sA.x * w1;
          a0[1] += sA.y * w0; a1[1] += sA.y * w1;
          a0[2] += sA.z * w0; a1[2] += sA.z * w1;
          a0[3] += sA.w * w0; a1[3] += sA.w * w1;
          a0[4] += sB.x * w0; a1[4] += sB.x * w1;
          a0[5] += sB.y * w0; a1[5] += sB.y * w1;
          a0[6] += sB.z * w0; a1[6] += sB.z * w1;
          a0[7] += sB.w * w0; a1[7] += sB.w * w1;
        }
#pragma unroll
        for (int n = 0; n < NB; n++) {
          float x0 = a0[n], x1 = a1[n];
          unsigned h0 = __float_as_uint(x0) >> 16, h1 = __float_as_uint(x1) >> 16;
          unsigned l0 = __float_as_uint(x0 - __uint_as_float(h0 << 16)) >> 16;
          unsigned l1 = __float_as_uint(x1 - __uint_as_float(h1 << 16)) >> 16;
          int ub = bufo + ((n * 4 + th * 2) * 64 + tl) * 8 + 2 * jg;
          *(unsigned*)&sTq[ub] = h0 | (h1 << 16);        // sp=0 (hi)
          *(unsigned*)&sTq[ub + 512] = l0 | (l1 << 16);  // sp=1 (lo)
        }
      }
      __syncthreads();  // the ONLY barrier per kc: write(kc) before read(kc);
                        // also orders read(kc-1) before write(kc+1)
      // ---- edge MFMA for this kc on TPW tiles ----
#pragma unroll
      for (int ti = 0; ti < TPW; ti++) {
        int idx16 = cbase + (wid * TPW + ti) * 16;
        if (idx16 < end) {
          const ushort_t* ah = aq_hi + (size_t)(idx16 + r) * 128 + kc * 32 + kg;
          const ushort_t* al = aq_lo + (size_t)(idx16 + r) * 128 + kc * 32 + kg;
          bf16x8 Ah = *(const bf16x8*)ah;
          bf16x8 Al = *(const bf16x8*)al;
          int b = bufo + tn[ti] * 2048 + l * 8;
          bf16x8 B0h = *(const bf16x8*)&sTq[b];
          bf16x8 B0l = *(const bf16x8*)&sTq[b + 512];
          bf16x8 B1h = *(const bf16x8*)&sTq[b + 1024];
          bf16x8 B1l = *(const bf16x8*)&sTq[b + 1536];
          acc[ti][0] = __builtin_amdgcn_mfma_f32_16x16x32_bf16(Ah, B0h, acc[ti][0], 0, 0, 0);
          acc[ti][0] = __builtin_amdgcn_mfma_f32_16x16x32_bf16(Al, B0h, acc[ti][0], 0, 0, 0);
          acc[ti][0] = __builtin_amdgcn_mfma_f32_16x16x32_bf16(Ah, B0l, acc[ti][0], 0, 0, 0);
          acc[ti][1] = __builtin_amdgcn_mfma_f32_16x16x32_bf16(Ah, B1h, acc[ti][1], 0, 0, 0);
          acc[ti][1] = __builtin_amdgcn_mfma_f32_16x16x32_bf16(Al, B1h, acc[ti][1], 0, 0, 0);
          acc[ti][1] = __builtin_amdgcn_mfma_f32_16x16x32_bf16(Ah, B1l, acc[ti][1], 0, 0, 0);
        }
      }
    }
    // ---- flush: one atomic per real (e,o) ----
    int er = (l >> 4) << 2;
    int c = l & 15;
#pragma unroll
    for (int ti = 0; ti < TPW; ti++) {
      int idx16 = cbase + (wid * TPW + ti) * 16;
      if (idx16 < end) {
#pragma unroll
        for (int j = 0; j < 4; j++) {
          int idx = idx16 + er + j;
          int d = dstp[idx];
          if (d >= 0) {
            atomicAdd(&agg[(size_t)d * 32 + c], acc[ti][0][j] + sTb[tn[ti]][c]);
            atomicAdd(&agg[(size_t)d * 32 + c + 16], acc[ti][1][j] + sTb[tn[ti]][c + 16]);
          }
        }
      }
    }
    __syncthreads();  // flush's sTb/sTq-era reads done before next chunk's
                      // first T-write reuses buffer 0
  }
}

// ------- fused agg-read + GRU + agg-rezero: block = 8 nodes x 32 o ---------
__global__ __launch_bounds__(256) void k_agru(
    float* __restrict__ agg, const float* __restrict__ cbias,
    const float* __restrict__ wih, const float* __restrict__ whh,
    const float* __restrict__ bih, const float* __restrict__ bhh,
    float* __restrict__ hseq, int nV) {
  __shared__ float swT[2][32 * 97];
  __shared__ float sb[2][96], scb[32];
  __shared__ float sx[8][32], shd[8][32];
  int t = threadIdx.x;
  int v0 = blockIdx.x * 8;
  for (int idx = t; idx < 3072; idx += 256) {
    int row = idx >> 5, i = idx & 31;
    swT[0][i * 97 + row] = wih[idx];
    swT[1][i * 97 + row] = whh[idx];
  }
  if (t < 96) { sb[0][t] = bih[t]; sb[1][t] = bhh[t]; }
  if (t < 32) scb[t] = cbias[t];
  {
    int n = t >> 5, v = v0 + n, j = t & 31;
    shd[n][j] = (v < nV) ? hseq[(size_t)v * 32 + j] : 0.f;
    float av = 0.f;
    if (v < nV) {
      av = agg[(size_t)v * 32 + j];
      agg[(size_t)v * 32 + j] = 0.f;  // re-zero for next step's atomics
    }
    sx[n][j] = (v < nV) ? fmaxf(av + cbias[j], 0.f) : 0.f;
  }
  __syncthreads();
  int n = t >> 5, o = t & 31;
  int v = v0 + n;
  if (v >= nV) return;
  float gir = sb[0][o], giz = sb[0][32 + o], gin = sb[0][64 + o];
  float ghr = sb[1][o], ghz = sb[1][32 + o], ghn = sb[1][64 + o];
#pragma unroll
  for (int i = 0; i < 32; i++) {
    float xi = sx[n][i], hi = shd[n][i];
    gir += xi * swT[0][i * 97 + o];
    giz += xi * swT[0][i * 97 + 32 + o];
    gin += xi * swT[0][i * 97 + 64 + o];
    ghr += hi * swT[1][i * 97 + o];
    ghz += hi * swT[1][i * 97 + 32 + o];
    ghn += hi * swT[1][i * 97 + 64 + o];
  }
  float r = 1.f / (1.f + __expf(-(gir + ghr)));
  float z = 1.f / (1.f + __expf(-(giz + ghz)));
  float ng = tanhf(gin + r * ghn);
  hseq[(size_t)v * 32 + o] = (1.f - z) * ng + z * shd[n][o];
}

// ---------------- decoder: out = relu(h@dw1+db1)@dw2+db2  (V x 64) ---------
__global__ __launch_bounds__(256) void k_dec(
    const float* __restrict__ hseq, const float* __restrict__ w1,
    const float* __restrict__ b1, const float* __restrict__ w2,
    const float* __restrict__ b2, float* __restrict__ out, int nV) {
  __shared__ float sw1[1024], sb1[32], sw2[2048], sb2[64];
  __shared__ float sx[4][32], st1[4][32];
  int t = threadIdx.x;
  int v0 = blockIdx.x * 4;
  for (int i = t; i < 1024; i += 256) sw1[i] = w1[i];
  for (int i = t; i < 2048; i += 256) sw2[i] = w2[i];
  if (t < 32) sb1[t] = b1[t];
  if (t < 64) sb2[t] = b2[t];
  if (t < 128) {
    int g = v0 * 32 + t;
    sx[t >> 5][t & 31] = (g < nV * 32) ? hseq[g] : 0.f;
  }
  __syncthreads();
  if (t < 128) {
    int n = t >> 5, j = t & 31;
    float s = sb1[j];
#pragma unroll
    for (int i = 0; i < 32; i++) s += sx[n][i] * sw1[i * 32 + j];
    st1[n][j] = fmaxf(s, 0.f);
  }
  __syncthreads();
  int n = t >> 6, j = t & 63;
  float s = sb2[j];
#pragma unroll
  for (int i = 0; i < 32; i++) s += st1[n][i] * sw2[i * 64 + j];
  if (v0 + n < nV) out[(size_t)(v0 + n) * 64 + j] = s;
}

extern "C" void kernel_launch(void* const* d_in, const int* in_sizes, int n_in,
                              void* d_out, int out_size, void* d_ws, size_t ws_size,
                              hipStream_t stream) {
  const float* node_feats = (const float*)d_in[0];
  const float* edge_feats = (const float*)d_in[1];
  const int* src = (const int*)d_in[2];
  const int* dst = (const int*)d_in[3];
  const float* proj_w1 = (const float*)d_in[4];
  const float* proj_b1 = (const float*)d_in[5];
  const float* proj_w2 = (const float*)d_in[6];
  const float* proj_b2 = (const float*)d_in[7];
  const float* e_w1 = (const float*)d_in[8];
  const float* e_b1 = (const float*)d_in[9];
  const float* e_w2 = (const float*)d_in[10];
  const float* e_b2 = (const float*)d_in[11];
  const float* conv_bias = (const float*)d_in[12];
  const float* gru_wih = (const float*)d_in[13];
  const float* gru_whh = (const float*)d_in[14];
  const float* gru_bih = (const float*)d_in[15];
  const float* gru_bhh = (const float*)d_in[16];
  const float* dec_w1 = (const float*)d_in[17];
  const float* dec_b1 = (const float*)d_in[18];
  const float* dec_w2 = (const float*)d_in[19];
  const float* dec_b2 = (const float*)d_in[20];
  float* out = (float*)d_out;

  const int nV = in_sizes[0] / 32;
  const int nE = in_sizes[2];
  // worst-case 16-padded idx space
  const int S = (nE + 15 * nV + 255) & ~255;

  // workspace carve-up (~206 MB worst case; proven-safe ~208)
  char* base = (char*)d_ws;
  size_t off = 0;
  auto carve = [&](size_t bytes) {
    void* r = base + off;
    off = (off + bytes + 255) & ~(size_t)255;
    return r;
  };
  ushort_t* aq_hi = (ushort_t*)carve((size_t)S * 128 * 2);
  ushort_t* aq_lo = (ushort_t*)carve((size_t)S * 128 * 2);
  float* hseq = (float*)carve((size_t)nV * 32 * 4);
  float* agg = (float*)carve((size_t)nV * 32 * 4);
  int* countsS = (int*)carve((size_t)nV * 4);
  int* rp16 = (int*)carve((size_t)(nV + 1) * 4);
  int* curS = (int*)carve((size_t)nV * 4);
  int* pose = (int*)carve((size_t)nE * 4);
  int* dstp = (int*)carve((size_t)S * 4);
  (void)ws_size;

  const int TB = 256;
  int gE = (nE + TB - 1) / TB;
  int g8 = (nV + 7) / 8;
  int g4 = (nV + 3) / 4;
  int gStep = (nV + NB - 1) / NB;

  // setup
  k_proj<<<g8, TB, 0, stream>>>(node_feats, proj_w1, proj_b1, proj_w2, proj_b2, hseq, nV);
  hipMemsetAsync(countsS, 0, (size_t)nV * 4, stream);
  hipMemsetAsync(dstp, 0xFF, (size_t)S * 4, stream);  // -1 sentinels
  hipMemsetAsync(agg, 0, (size_t)nV * 32 * 4, stream);  // covers 0xAA poison
  k_count<<<gE, TB, 0, stream>>>(src, countsS, nE);
  k_scan<<<1, 1024, 0, stream>>>(countsS, rp16, nV);
  k_copy<<<(nV + TB - 1) / TB, TB, 0, stream>>>(rp16, curS, nV);
  k_scatter<<<gE, TB, 0, stream>>>(src, dst, curS, pose, dstp, nE);
  k_edgebuild<<<(nE + 63) / 64, TB, 0, stream>>>(edge_feats, e_w1, e_b1, pose,
                                                 aq_hi, aq_lo, nE);

  // 6 message-passing steps (k_agru re-zeroes agg for the next step)
  for (int step = 0; step < 6; step++) {
    k_step<<<gStep, 512, 0, stream>>>(hseq, e_w2, e_b2, aq_hi, aq_lo, rp16, dstp,
                                      agg, nV);
    k_agru<<<g8, TB, 0, stream>>>(agg, conv_bias, gru_wih, gru_whh,
                                  gru_bih, gru_bhh, hseq, nV);
  }

  // decoder
  k_dec<<<g4, TB, 0, stream>>>(hseq, dec_w1, dec_b1, dec_w2, dec_b2, out, nV);
}

// Round 23
// 824.305 us; speedup vs baseline: 1.8604x; 1.0035x over previous
//
#include <hip/hip_runtime.h>
#include <hip/hip_bf16.h>

// MPNN GNN: V=12500 (feat 32), E=200000 (feat 16), H=32, 6 steps.
// msg[e,o] = sum_k a[e,k]*T[src[e],k,o] + Tb[src[e],o],  a loop-invariant.
// R23: R22 base (827us, dbuf sTq, 1 barrier/kc) + (1) end-of-chunk barrier
// DELETED (provably redundant: last buf0 read is kc=2 MFMA, ordered before
// any wave passes barrier(kc=3); flush touches no sTq) and (2) k_copy fused
// into k_scan. Barriers/chunk 5 -> 4.
// Ledger: R15 remap(-), R17 1024t(-), R19 256t(-), R20 hoist(-), R18 b128(+),
// R22 dbuf(+2%). Proven stack: split-bf16 3-GEMM MFMA (absmax 0.0156),
// kc-streamed dbuf T, j-split zero-redundancy w2 loads (R14 map), hidden
// LDS-write conflict, dense edgebuild + pose scatter, one atomic per real
// (e,o), agg-rezero in k_agru.

#define NB 8   // src nodes per k_step block
#define TPW 2  // 16-edge tiles per wave per chunk
#define CAP (8 * TPW * 16)  // 256 padded slots per chunk

typedef __attribute__((ext_vector_type(8))) short bf16x8;
typedef __attribute__((ext_vector_type(4))) float f32x4;
typedef unsigned short ushort_t;

// ---------------- node projection: h = relu(nf@w1+b1)@w2+b2 ----------------
__global__ __launch_bounds__(256) void k_proj(
    const float* __restrict__ nf, const float* __restrict__ w1,
    const float* __restrict__ b1, const float* __restrict__ w2,
    const float* __restrict__ b2, float* __restrict__ hseq, int nV) {
  __shared__ float sw1[1024], sw2[1024], sb1[32], sb2[32];
  __shared__ float sx[8][32], st1[8][32];
  int t = threadIdx.x;
  int v0 = blockIdx.x * 8;
  for (int i = t; i < 1024; i += 256) { sw1[i] = w1[i]; sw2[i] = w2[i]; }
  if (t < 32) { sb1[t] = b1[t]; sb2[t] = b2[t]; }
  {
    int g = v0 * 32 + t;
    sx[t >> 5][t & 31] = (g < nV * 32) ? nf[g] : 0.f;
  }
  __syncthreads();
  int n = t >> 5, j = t & 31;
  float s = sb1[j];
#pragma unroll
  for (int i = 0; i < 32; i++) s += sx[n][i] * sw1[i * 32 + j];
  st1[n][j] = fmaxf(s, 0.f);
  __syncthreads();
  float h = sb2[j];
#pragma unroll
  for (int i = 0; i < 32; i++) h += st1[n][i] * sw2[i * 32 + j];
  if (v0 + n < nV) hseq[(size_t)(v0 + n) * 32 + j] = h;
}

// ---------------- CSR by src, padded to multiples of 16 --------------------
__global__ __launch_bounds__(256) void k_count(const int* __restrict__ key,
                                               int* __restrict__ counts, int nE) {
  int e = blockIdx.x * 256 + threadIdx.x;
  if (e < nE) atomicAdd(&counts[key[e]], 1);
}

// scan + cursor init fused (R23)
__global__ __launch_bounds__(1024) void k_scan(const int* __restrict__ counts,
                                               int* __restrict__ row_ptr,
                                               int* __restrict__ cursor, int nV) {
  __shared__ int buf[1024];
  __shared__ int s_off;
  int t = threadIdx.x;
  if (t == 0) s_off = 0;
  __syncthreads();
  for (int base = 0; base < nV; base += 1024) {
    int x = (base + t < nV) ? ((counts[base + t] + 15) & ~15) : 0;  // pad to 16
    buf[t] = x;
    __syncthreads();
    for (int d = 1; d < 1024; d <<= 1) {
      int v2 = (t >= d) ? buf[t - d] : 0;
      __syncthreads();
      buf[t] += v2;
      __syncthreads();
    }
    int incl = buf[t];
    int off = s_off;
    __syncthreads();
    if (base + t < nV) {
      int ex = off + incl - x;  // exclusive
      row_ptr[base + t] = ex;
      cursor[base + t] = ex;
    }
    if (t == 1023) s_off = off + incl;
    __syncthreads();
  }
  if (t == 0) row_ptr[nV] = s_off;
}

// scatter: pose[e]=padded slot of edge e; dstp[slot]=dst (pads stay -1)
__global__ __launch_bounds__(256) void k_scatter(const int* __restrict__ key,
                                                 const int* __restrict__ dst,
                                                 int* __restrict__ cursor,
                                                 int* __restrict__ pose,
                                                 int* __restrict__ dstp, int nE) {
  int e = blockIdx.x * 256 + threadIdx.x;
  if (e < nE) {
    int p = atomicAdd(&cursor[key[e]], 1);
    pose[e] = p;
    dstp[p] = dst[e];
  }
}

// ------- edge MLP, dense over real edges -> split bf16 planes --------------
__global__ __launch_bounds__(256) void k_edgebuild(
    const float* __restrict__ ef, const float* __restrict__ w1,
    const float* __restrict__ b1, const int* __restrict__ pose,
    ushort_t* __restrict__ aq_hi, ushort_t* __restrict__ aq_lo, int nE) {
  __shared__ float sw1[16 * 128], sb1[128];
  __shared__ float sef[64][17];
  __shared__ int spos[64];
  int t = threadIdx.x;
  int e0 = blockIdx.x * 64;
  if (e0 >= nE) return;
  for (int i = t; i < 2048; i += 256) sw1[i] = w1[i];
  if (t < 128) sb1[t] = b1[t];
  for (int i = t; i < 1024; i += 256) {
    int g = e0 * 16 + i;
    sef[i >> 4][i & 15] = (g < nE * 16) ? ef[g] : 0.f;
  }
  if (t < 64) spos[t] = (e0 + t < nE) ? pose[e0 + t] : 0;
  __syncthreads();
  int c = t & 127;
#pragma unroll 1
  for (int it = 0; it < 32; ++it) {
    int el = it * 2 + (t >> 7);
    if (e0 + el < nE) {
      float s = sb1[c];
#pragma unroll
      for (int i = 0; i < 16; i++) s += sef[el][i] * sw1[i * 128 + c];
      s = fmaxf(s, 0.f);
      unsigned u = __float_as_uint(s);
      unsigned hb = u >> 16;
      float fh = __uint_as_float(hb << 16);
      unsigned lb = __float_as_uint(s - fh) >> 16;
      size_t p = (size_t)spos[el] * 128 + c;
      aq_hi[p] = (ushort_t)hb;
      aq_lo[p] = (ushort_t)lb;
    }
  }
}

// ---------------- per-step: kc-streamed T (j-split) + MFMA edges -----------
// Double-buffered LDS sTq (2 x 32 KB): buffer kc&1 holds quarter frags,
// ushort[(n*4 + h*2 + sp)*512 + l*8 + j] = T[n][kc*32 + (l>>4)*8 + j]
// [(l&15)+16h], sp: 0=hi 1=lo. ONE barrier per kc; no end-of-chunk barrier
// (last buf0 read = kc=2 MFMA is ordered before any wave passes barrier
// kc=3; flush touches no sTq).
// T-phase map (R14/R16): jg=t>>7, th=(t>>6)&1, tl=t&63; b128 h-reads (R18).
__global__ __launch_bounds__(512) void k_step(
    const float* __restrict__ hseq, const float* __restrict__ w2,
    const float* __restrict__ b2, const ushort_t* __restrict__ aq_hi,
    const ushort_t* __restrict__ aq_lo, const int* __restrict__ rp16,
    const int* __restrict__ dstp, float* __restrict__ agg, int nV) {
  __shared__ unsigned short sTq[32768];  // 64 KB, two 16384-ushort buffers
  __shared__ float sh[NB][32];     // [n][i] — Tb phase
  __shared__ float sh_t[32][NB];   // [i][n] — T phase (b128-readable)
  __shared__ float sTb[NB][32];
  __shared__ int s_rp[NB + 1];
  int t = threadIdx.x;
  int v0 = blockIdx.x * NB;
  if (t <= NB) {
    int v = v0 + t;
    if (v > nV) v = nV;
    s_rp[t] = rp16[v];
  }
  if (t < NB * 32) {
    int n = t >> 5, i = t & 31, v = v0 + n;
    float hv = (v < nV) ? hseq[(size_t)v * 32 + i] : 0.f;
    sh[n][i] = hv;
    sh_t[i][n] = hv;
  }
  __syncthreads();
  int beg = s_rp[0], end = s_rp[NB];
  if (beg == end) return;  // block-uniform

  if (t < NB * 32) {  // Tb[n][o] = sum_i h[n][i]*e_b2[i*32+o]
    int n = t >> 5, o = t & 31;
    float s = 0.f;
#pragma unroll
    for (int i = 0; i < 32; i++) s += sh[n][i] * b2[i * 32 + o];
    sTb[n][o] = s;
  }

  // thread constants — edge phase
  int wid = t >> 6, l = t & 63;
  int r = l & 15, kg = (l >> 4) << 3;
  // thread constants — T phase (j-split, R14 mapping)
  int jg = t >> 7;                  // 0..3: owns j = {2jg, 2jg+1}
  int th = (t >> 6) & 1;            // h half
  int tl = t & 63;                  // fragment lane
  int tc = (tl & 15) + th * 16;     // output column c
  int tkr = (tl >> 4) << 3;         // k row-group offset

  int nrun = 0;  // monotonic node cursor for this wave's tiles
  for (int cbase = beg; cbase < end; cbase += CAP) {
    int tn[TPW];
#pragma unroll
    for (int ti = 0; ti < TPW; ti++) {
      int idx16 = cbase + (wid * TPW + ti) * 16;
      if (idx16 < end) {
        while (idx16 >= s_rp[nrun + 1]) nrun++;
        tn[ti] = nrun;
      } else
        tn[ti] = NB - 1;
    }
    f32x4 acc[TPW][2];
#pragma unroll
    for (int ti = 0; ti < TPW; ti++)
#pragma unroll
      for (int hh = 0; hh < 2; hh++) acc[ti][hh] = (f32x4){0.f, 0.f, 0.f, 0.f};

#pragma unroll 1
    for (int kc = 0; kc < 4; kc++) {
      int bufo = (kc & 1) << 14;  // 0 or 16384 ushorts
      // ---- T-quarter, j-split: disjoint w2 loads; b128 h reads ----
      {
        int kbase = kc * 32 + tkr + 2 * jg;
        const float* wb = w2 + (size_t)kbase * 1024 + tc;  // + jj*1024 + i*32
        float a0[NB], a1[NB];
#pragma unroll
        for (int n = 0; n < NB; n++) { a0[n] = 0.f; a1[n] = 0.f; }
#pragma unroll 4
        for (int i = 0; i < 32; i++) {
          float w0 = wb[i * 32];
          float w1 = wb[1024 + i * 32];
          float4 sA = *(const float4*)&sh_t[i][0];
          float4 sB = *(const float4*)&sh_t[i][4];
          a0[0] += sA.x * w0; a1[0] += sA.x * w1;
          a0[1] += sA.y * w0; a1[1] += sA.y * w1;
          a0[2] += sA.z * w0; a1[2] += sA.z * w1;
          a0[3] += sA.w * w0; a1[3] += sA.w * w1;
          a0[4] += sB.x * w0; a1[4] += sB.x * w1;
          a0[5] += sB.y * w0; a1[5] += sB.y * w1;
          a0[6] += sB.z * w0; a1[6] += sB.z * w1;
          a0[7] += sB.w * w0; a1[7] += sB.w * w1;
        }
#pragma unroll
        for (int n = 0; n < NB; n++) {
          float x0 = a0[n], x1 = a1[n];
          unsigned h0 = __float_as_uint(x0) >> 16, h1 = __float_as_uint(x1) >> 16;
          unsigned l0 = __float_as_uint(x0 - __uint_as_float(h0 << 16)) >> 16;
          unsigned l1 = __float_as_uint(x1 - __uint_as_float(h1 << 16)) >> 16;
          int ub = bufo + ((n * 4 + th * 2) * 64 + tl) * 8 + 2 * jg;
          *(unsigned*)&sTq[ub] = h0 | (h1 << 16);        // sp=0 (hi)
          *(unsigned*)&sTq[ub + 512] = l0 | (l1 << 16);  // sp=1 (lo)
        }
      }
      __syncthreads();  // the ONLY barrier per kc: write(kc) before read(kc);
                        // also orders read(kc-1) before write(kc+1)
      // ---- edge MFMA for this kc on TPW tiles ----
#pragma unroll
      for (int ti = 0; ti < TPW; ti++) {
        int idx16 = cbase + (wid * TPW + ti) * 16;
        if (idx16 < end) {
          const ushort_t* ah = aq_hi + (size_t)(idx16 + r) * 128 + kc * 32 + kg;
          const ushort_t* al = aq_lo + (size_t)(idx16 + r) * 128 + kc * 32 + kg;
          bf16x8 Ah = *(const bf16x8*)ah;
          bf16x8 Al = *(const bf16x8*)al;
          int b = bufo + tn[ti] * 2048 + l * 8;
          bf16x8 B0h = *(const bf16x8*)&sTq[b];
          bf16x8 B0l = *(const bf16x8*)&sTq[b + 512];
          bf16x8 B1h = *(const bf16x8*)&sTq[b + 1024];
          bf16x8 B1l = *(const bf16x8*)&sTq[b + 1536];
          acc[ti][0] = __builtin_amdgcn_mfma_f32_16x16x32_bf16(Ah, B0h, acc[ti][0], 0, 0, 0);
          acc[ti][0] = __builtin_amdgcn_mfma_f32_16x16x32_bf16(Al, B0h, acc[ti][0], 0, 0, 0);
          acc[ti][0] = __builtin_amdgcn_mfma_f32_16x16x32_bf16(Ah, B0l, acc[ti][0], 0, 0, 0);
          acc[ti][1] = __builtin_amdgcn_mfma_f32_16x16x32_bf16(Ah, B1h, acc[ti][1], 0, 0, 0);
          acc[ti][1] = __builtin_amdgcn_mfma_f32_16x16x32_bf16(Al, B1h, acc[ti][1], 0, 0, 0);
          acc[ti][1] = __builtin_amdgcn_mfma_f32_16x16x32_bf16(Ah, B1l, acc[ti][1], 0, 0, 0);
        }
      }
    }
    // ---- flush: one atomic per real (e,o); no sTq access, no barrier ----
    int er = (l >> 4) << 2;
    int c = l & 15;
#pragma unroll
    for (int ti = 0; ti < TPW; ti++) {
      int idx16 = cbase + (wid * TPW + ti) * 16;
      if (idx16 < end) {
#pragma unroll
        for (int j = 0; j < 4; j++) {
          int idx = idx16 + er + j;
          int d = dstp[idx];
          if (d >= 0) {
            atomicAdd(&agg[(size_t)d * 32 + c], acc[ti][0][j] + sTb[tn[ti]][c]);
            atomicAdd(&agg[(size_t)d * 32 + c + 16], acc[ti][1][j] + sTb[tn[ti]][c + 16]);
          }
        }
      }
    }
  }
}

// ------- fused agg-read + GRU + agg-rezero: block = 8 nodes x 32 o ---------
__global__ __launch_bounds__(256) void k_agru(
    float* __restrict__ agg, const float* __restrict__ cbias,
    const float* __restrict__ wih, const float* __restrict__ whh,
    const float* __restrict__ bih, const float* __restrict__ bhh,
    float* __restrict__ hseq, int nV) {
  __shared__ float swT[2][32 * 97];
  __shared__ float sb[2][96], scb[32];
  __shared__ float sx[8][32], shd[8][32];
  int t = threadIdx.x;
  int v0 = blockIdx.x * 8;
  for (int idx = t; idx < 3072; idx += 256) {
    int row = idx >> 5, i = idx & 31;
    swT[0][i * 97 + row] = wih[idx];
    swT[1][i * 97 + row] = whh[idx];
  }
  if (t < 96) { sb[0][t] = bih[t]; sb[1][t] = bhh[t]; }
  if (t < 32) scb[t] = cbias[t];
  {
    int n = t >> 5, v = v0 + n, j = t & 31;
    shd[n][j] = (v < nV) ? hseq[(size_t)v * 32 + j] : 0.f;
    float av = 0.f;
    if (v < nV) {
      av = agg[(size_t)v * 32 + j];
      agg[(size_t)v * 32 + j] = 0.f;  // re-zero for next step's atomics
    }
    sx[n][j] = (v < nV) ? fmaxf(av + cbias[j], 0.f) : 0.f;
  }
  __syncthreads();
  int n = t >> 5, o = t & 31;
  int v = v0 + n;
  if (v >= nV) return;
  float gir = sb[0][o], giz = sb[0][32 + o], gin = sb[0][64 + o];
  float ghr = sb[1][o], ghz = sb[1][32 + o], ghn = sb[1][64 + o];
#pragma unroll
  for (int i = 0; i < 32; i++) {
    float xi = sx[n][i], hi = shd[n][i];
    gir += xi * swT[0][i * 97 + o];
    giz += xi * swT[0][i * 97 + 32 + o];
    gin += xi * swT[0][i * 97 + 64 + o];
    ghr += hi * swT[1][i * 97 + o];
    ghz += hi * swT[1][i * 97 + 32 + o];
    ghn += hi * swT[1][i * 97 + 64 + o];
  }
  float r = 1.f / (1.f + __expf(-(gir + ghr)));
  float z = 1.f / (1.f + __expf(-(giz + ghz)));
  float ng = tanhf(gin + r * ghn);
  hseq[(size_t)v * 32 + o] = (1.f - z) * ng + z * shd[n][o];
}

// ---------------- decoder: out = relu(h@dw1+db1)@dw2+db2  (V x 64) ---------
__global__ __launch_bounds__(256) void k_dec(
    const float* __restrict__ hseq, const float* __restrict__ w1,
    const float* __restrict__ b1, const float* __restrict__ w2,
    const float* __restrict__ b2, float* __restrict__ out, int nV) {
  __shared__ float sw1[1024], sb1[32], sw2[2048], sb2[64];
  __shared__ float sx[4][32], st1[4][32];
  int t = threadIdx.x;
  int v0 = blockIdx.x * 4;
  for (int i = t; i < 1024; i += 256) sw1[i] = w1[i];
  for (int i = t; i < 2048; i += 256) sw2[i] = w2[i];
  if (t < 32) sb1[t] = b1[t];
  if (t < 64) sb2[t] = b2[t];
  if (t < 128) {
    int g = v0 * 32 + t;
    sx[t >> 5][t & 31] = (g < nV * 32) ? hseq[g] : 0.f;
  }
  __syncthreads();
  if (t < 128) {
    int n = t >> 5, j = t & 31;
    float s = sb1[j];
#pragma unroll
    for (int i = 0; i < 32; i++) s += sx[n][i] * sw1[i * 32 + j];
    st1[n][j] = fmaxf(s, 0.f);
  }
  __syncthreads();
  int n = t >> 6, j = t & 63;
  float s = sb2[j];
#pragma unroll
  for (int i = 0; i < 32; i++) s += st1[n][i] * sw2[i * 64 + j];
  if (v0 + n < nV) out[(size_t)(v0 + n) * 64 + j] = s;
}

extern "C" void kernel_launch(void* const* d_in, const int* in_sizes, int n_in,
                              void* d_out, int out_size, void* d_ws, size_t ws_size,
                              hipStream_t stream) {
  const float* node_feats = (const float*)d_in[0];
  const float* edge_feats = (const float*)d_in[1];
  const int* src = (const int*)d_in[2];
  const int* dst = (const int*)d_in[3];
  const float* proj_w1 = (const float*)d_in[4];
  const float* proj_b1 = (const float*)d_in[5];
  const float* proj_w2 = (const float*)d_in[6];
  const float* proj_b2 = (const float*)d_in[7];
  const float* e_w1 = (const float*)d_in[8];
  const float* e_b1 = (const float*)d_in[9];
  const float* e_w2 = (const float*)d_in[10];
  const float* e_b2 = (const float*)d_in[11];
  const float* conv_bias = (const float*)d_in[12];
  const float* gru_wih = (const float*)d_in[13];
  const float* gru_whh = (const float*)d_in[14];
  const float* gru_bih = (const float*)d_in[15];
  const float* gru_bhh = (const float*)d_in[16];
  const float* dec_w1 = (const float*)d_in[17];
  const float* dec_b1 = (const float*)d_in[18];
  const float* dec_w2 = (const float*)d_in[19];
  const float* dec_b2 = (const float*)d_in[20];
  float* out = (float*)d_out;

  const int nV = in_sizes[0] / 32;
  const int nE = in_sizes[2];
  // worst-case 16-padded idx space
  const int S = (nE + 15 * nV + 255) & ~255;

  // workspace carve-up (~206 MB worst case; proven-safe ~208)
  char* base = (char*)d_ws;
  size_t off = 0;
  auto carve = [&](size_t bytes) {
    void* r = base + off;
    off = (off + bytes + 255) & ~(size_t)255;
    return r;
  };
  ushort_t* aq_hi = (ushort_t*)carve((size_t)S * 128 * 2);
  ushort_t* aq_lo = (ushort_t*)carve((size_t)S * 128 * 2);
  float* hseq = (float*)carve((size_t)nV * 32 * 4);
  float* agg = (float*)carve((size_t)nV * 32 * 4);
  int* countsS = (int*)carve((size_t)nV * 4);
  int* rp16 = (int*)carve((size_t)(nV + 1) * 4);
  int* curS = (int*)carve((size_t)nV * 4);
  int* pose = (int*)carve((size_t)nE * 4);
  int* dstp = (int*)carve((size_t)S * 4);
  (void)ws_size;

  const int TB = 256;
  int gE = (nE + TB - 1) / TB;
  int g8 = (nV + 7) / 8;
  int g4 = (nV + 3) / 4;
  int gStep = (nV + NB - 1) / NB;

  // setup
  k_proj<<<g8, TB, 0, stream>>>(node_feats, proj_w1, proj_b1, proj_w2, proj_b2, hseq, nV);
  hipMemsetAsync(countsS, 0, (size_t)nV * 4, stream);
  hipMemsetAsync(dstp, 0xFF, (size_t)S * 4, stream);  // -1 sentinels
  hipMemsetAsync(agg, 0, (size_t)nV * 32 * 4, stream);  // covers 0xAA poison
  k_count<<<gE, TB, 0, stream>>>(src, countsS, nE);
  k_scan<<<1, 1024, 0, stream>>>(countsS, rp16, curS, nV);
  k_scatter<<<gE, TB, 0, stream>>>(src, dst, curS, pose, dstp, nE);
  k_edgebuild<<<(nE + 63) / 64, TB, 0, stream>>>(edge_feats, e_w1, e_b1, pose,
                                                 aq_hi, aq_lo, nE);

  // 6 message-passing steps (k_agru re-zeroes agg for the next step)
  for (int step = 0; step < 6; step++) {
    k_step<<<gStep, 512, 0, stream>>>(hseq, e_w2, e_b2, aq_hi, aq_lo, rp16, dstp,
                                      agg, nV);
    k_agru<<<g8, TB, 0, stream>>>(agg, conv_bias, gru_wih, gru_whh,
                                  gru_bih, gru_bhh, hseq, nV);
  }

  // decoder
  k_dec<<<g4, TB, 0, stream>>>(hseq, dec_w1, dec_b1, dec_w2, dec_b2, out, nV);
}